// Round 1
// baseline (453.350 us; speedup 1.0000x reference)
//
#include <hip/hip_runtime.h>
#include <hip/hip_bf16.h>

#define B_ 4
#define T_ 2048
#define D_ 2048
#define DV_ 1024
#define TIMG_ 8
#define NLAT_ 64
#define H_ 16
#define DH_ 64
#define INNER_ 1024
#define J_ (TIMG_ * NLAT_)  // 512

using f32x4 = __attribute__((ext_vector_type(4))) float;
using bf16x8 = __attribute__((ext_vector_type(8))) short;

__device__ __forceinline__ unsigned short f2bf(float f) {
  union { float f; unsigned int u; } c{f};
  unsigned int r = c.u + 0x7FFFu + ((c.u >> 16) & 1u);  // RNE
  return (unsigned short)(r >> 16);
}

// ---------------- media_locations scan -> img_idx (text_time-1) ----------------
__global__ __launch_bounds__(256) void scan_kernel(const void* __restrict__ locs,
                                                   int* __restrict__ img_idx) {
  __shared__ int sm[256];
  const int tid = threadIdx.x;
  const int b = blockIdx.x;
  const unsigned char* u8 = (const unsigned char*)locs;
  // dtype detection: count nonzero bytes in first B_*T_ bytes (safe for both layouts)
  int cnt = 0;
  for (int i = tid; i < B_ * T_; i += 256) cnt += (u8[i] != 0) ? 1 : 0;
  sm[tid] = cnt;
  __syncthreads();
  for (int off = 128; off > 0; off >>= 1) {
    if (tid < off) sm[tid] += sm[tid + off];
    __syncthreads();
  }
  const bool u8mode = (sm[0] == B_ * TIMG_);
  __syncthreads();

  const int base = b * T_ + tid * 8;
  const int* i32 = (const int*)locs;
  int v[8];
  int ts = 0;
#pragma unroll
  for (int j = 0; j < 8; ++j) {
    v[j] = u8mode ? (u8[base + j] != 0 ? 1 : 0) : (i32[base + j] != 0 ? 1 : 0);
    ts += v[j];
  }
  sm[tid] = ts;
  __syncthreads();
  // Hillis-Steele inclusive scan over 256 partials
  for (int off = 1; off < 256; off <<= 1) {
    int add = (tid >= off) ? sm[tid - off] : 0;
    __syncthreads();
    sm[tid] += add;
    __syncthreads();
  }
  int acc = sm[tid] - ts;  // exclusive prefix
#pragma unroll
  for (int j = 0; j < 8; ++j) {
    acc += v[j];
    img_idx[base + j] = acc - 1;  // -1 => no media yet
  }
}

// ---------------- LayerNorm (f32 in, bf16 out) ----------------
__global__ __launch_bounds__(256) void ln_kernel(const float* __restrict__ x,
                                                 const float* __restrict__ g,
                                                 const float* __restrict__ bta,
                                                 unsigned short* __restrict__ xn) {
  const int row = blockIdx.x;
  const int tid = threadIdx.x;
  const float4* xr = (const float4*)(x + (size_t)row * D_);
  float4 v0 = xr[tid];
  float4 v1 = xr[tid + 256];
  float s = v0.x + v0.y + v0.z + v0.w + v1.x + v1.y + v1.z + v1.w;
  float sq = v0.x * v0.x + v0.y * v0.y + v0.z * v0.z + v0.w * v0.w +
             v1.x * v1.x + v1.y * v1.y + v1.z * v1.z + v1.w * v1.w;
#pragma unroll
  for (int off = 32; off > 0; off >>= 1) {
    s += __shfl_xor(s, off);
    sq += __shfl_xor(sq, off);
  }
  __shared__ float ls[4], lq[4];
  const int lane = tid & 63, wave = tid >> 6;
  if (lane == 0) { ls[wave] = s; lq[wave] = sq; }
  __syncthreads();
  s = ls[0] + ls[1] + ls[2] + ls[3];
  sq = lq[0] + lq[1] + lq[2] + lq[3];
  const float mu = s * (1.0f / D_);
  const float rstd = rsqrtf(sq * (1.0f / D_) - mu * mu + 1e-5f);
  const float4* gv4 = (const float4*)g;
  const float4* bv4 = (const float4*)bta;
  ushort4* o4 = (ushort4*)(xn + (size_t)row * D_);
#pragma unroll
  for (int i = 0; i < 2; ++i) {
    const int idx = tid + i * 256;
    float4 vv = i == 0 ? v0 : v1;
    float4 gv = gv4[idx];
    float4 bv = bv4[idx];
    ushort4 o = make_ushort4(f2bf((vv.x - mu) * rstd * gv.x + bv.x),
                             f2bf((vv.y - mu) * rstd * gv.y + bv.y),
                             f2bf((vv.z - mu) * rstd * gv.z + bv.z),
                             f2bf((vv.w - mu) * rstd * gv.w + bv.w));
    o4[idx] = o;
  }
}

// ---------------- transpose + cast f32(RxC) -> bf16(CxR) ----------------
__global__ void tcast(const float* __restrict__ in, unsigned short* __restrict__ out,
                      int R, int C) {
  __shared__ float tile[32][33];
  const int bc = blockIdx.x * 32;
  const int br = blockIdx.y * 32;
  const int tx = threadIdx.x, ty = threadIdx.y;
#pragma unroll
  for (int i = ty; i < 32; i += 8)
    tile[i][tx] = in[(size_t)(br + i) * C + bc + tx];
  __syncthreads();
#pragma unroll
  for (int i = ty; i < 32; i += 8)
    out[(size_t)(bc + i) * R + br + tx] = f2bf(tile[tx][i]);
}

// ---------------- straight cast f32 -> bf16 (n4 float4 chunks) ----------------
__global__ void cast_bf16(const float* __restrict__ in, unsigned short* __restrict__ out,
                          int n4) {
  int i = blockIdx.x * blockDim.x + threadIdx.x;
  if (i >= n4) return;
  float4 v = ((const float4*)in)[i];
  ((ushort4*)out)[i] = make_ushort4(f2bf(v.x), f2bf(v.y), f2bf(v.z), f2bf(v.w));
}

// ---------------- bf16 MFMA GEMM: C(MxN,f32) = A(MxK) * BT(NxK)^T ----------------
__global__ __launch_bounds__(256) void gemm_bt(const unsigned short* __restrict__ A,
                                               const unsigned short* __restrict__ BT,
                                               float* __restrict__ C,
                                               int M, int N, int K) {
  __shared__ __align__(16) unsigned short As[128 * 64];
  __shared__ __align__(16) unsigned short Bs[128 * 64];
  const int tid = threadIdx.x;
  const int lane = tid & 63;
  const int wave = tid >> 6;
  const int gridN = N >> 7;
  const long row0 = (long)(blockIdx.x / gridN) << 7;
  const long col0 = (long)(blockIdx.x % gridN) << 7;
  const int wr = (wave >> 1) * 64;
  const int wc = (wave & 1) * 64;

  f32x4 acc[4][4] = {};

  for (int kt = 0; kt < K; kt += 64) {
    __syncthreads();
#pragma unroll
    for (int it = 0; it < 4; ++it) {
      const int ci = it * 256 + tid;
      const int r = ci >> 3;
      const int k8 = (ci & 7) << 3;
      const unsigned short* ga = A + (row0 + r) * K + kt + k8;
      const unsigned short* gb = BT + (col0 + r) * K + kt + k8;
      __builtin_amdgcn_global_load_lds(
          (const __attribute__((address_space(1))) unsigned int*)ga,
          (__attribute__((address_space(3))) unsigned int*)(As + ci * 8), 16, 0, 0);
      __builtin_amdgcn_global_load_lds(
          (const __attribute__((address_space(1))) unsigned int*)gb,
          (__attribute__((address_space(3))) unsigned int*)(Bs + ci * 8), 16, 0, 0);
    }
    asm volatile("s_waitcnt vmcnt(0)" ::: "memory");
    __syncthreads();
#pragma unroll
    for (int kk = 0; kk < 2; ++kk) {
      const int ko = kk * 32 + ((lane >> 4) << 3);
      const int ra = wr + (lane & 15);
      const int rb = wc + (lane & 15);
      bf16x8 af[4], bfr[4];
#pragma unroll
      for (int m = 0; m < 4; ++m)
        af[m] = *(const bf16x8*)(As + (ra + m * 16) * 64 + ko);
#pragma unroll
      for (int n = 0; n < 4; ++n)
        bfr[n] = *(const bf16x8*)(Bs + (rb + n * 16) * 64 + ko);
#pragma unroll
      for (int m = 0; m < 4; ++m)
#pragma unroll
        for (int n = 0; n < 4; ++n)
          acc[m][n] = __builtin_amdgcn_mfma_f32_16x16x32_bf16(af[m], bfr[n], acc[m][n], 0, 0, 0);
    }
  }
  const int cr = (lane >> 4) << 2;
  const int cc = lane & 15;
#pragma unroll
  for (int m = 0; m < 4; ++m)
#pragma unroll
    for (int n = 0; n < 4; ++n)
#pragma unroll
      for (int j = 0; j < 4; ++j)
        C[(row0 + wr + m * 16 + cr + j) * N + col0 + wc + n * 16 + cc] = acc[m][n][j];
}

// ---------------- masked cross-attention: one wave per (b,t,h) ----------------
__global__ __launch_bounds__(256) void attn_kernel(const float* __restrict__ q,
                                                   const float* __restrict__ kv,
                                                   const int* __restrict__ img_idx,
                                                   unsigned short* __restrict__ attn_out) {
  const int lane = threadIdx.x & 63;
  const int w = threadIdx.x >> 6;
  const int gid = blockIdx.x * 4 + w;
  const int h = gid & (H_ - 1);
  const int bt = gid >> 4;   // / H_
  const int b = bt >> 11;    // / T_
  const int img = img_idx[bt];
  unsigned short* op = attn_out + (size_t)bt * INNER_ + h * DH_;
  if (img < 0) { op[lane] = 0; return; }  // bf16 zero
  const float qv = q[(size_t)bt * INNER_ + h * DH_ + lane] * 0.125f;
  const float* Kb = kv + (size_t)(b * J_ + img * NLAT_) * (2 * INNER_) + h * DH_;
  const float4* Kr = (const float4*)(Kb + (size_t)lane * (2 * INNER_));
  float s = 0.f;
#pragma unroll
  for (int i = 0; i < 16; ++i) {
    float4 kk = Kr[i];
    s += __shfl(qv, 4 * i + 0) * kk.x;
    s += __shfl(qv, 4 * i + 1) * kk.y;
    s += __shfl(qv, 4 * i + 2) * kk.z;
    s += __shfl(qv, 4 * i + 3) * kk.w;
  }
  float mx = s;
#pragma unroll
  for (int off = 32; off > 0; off >>= 1) mx = fmaxf(mx, __shfl_xor(mx, off));
  const float p = __expf(s - mx);
  float sum = p;
#pragma unroll
  for (int off = 32; off > 0; off >>= 1) sum += __shfl_xor(sum, off);
  const float* Vb = Kb + INNER_;
  float o = 0.f;
#pragma unroll
  for (int r = 0; r < 64; ++r) o += __shfl(p, r) * Vb[(size_t)r * (2 * INNER_) + lane];
  op[lane] = f2bf(o / sum);
}

extern "C" void kernel_launch(void* const* d_in, const int* in_sizes, int n_in,
                              void* d_out, int out_size, void* d_ws, size_t ws_size,
                              hipStream_t stream) {
  const float* x = (const float*)d_in[0];
  const float* media = (const float*)d_in[1];
  const void* mloc = d_in[2];
  const float* gamma = (const float*)d_in[3];
  const float* beta = (const float*)d_in[4];
  const float* Wq = (const float*)d_in[5];
  const float* Wkv = (const float*)d_in[6];
  const float* Wout = (const float*)d_in[7];
  float* out = (float*)d_out;

  char* ws = (char*)d_ws;
  unsigned short* xn = (unsigned short*)(ws);                    // 33.5 MB (reused as attn_out)
  unsigned short* wqt = (unsigned short*)(ws + 33554432);        // 4 MB  (INNER x D)
  unsigned short* wkvt = (unsigned short*)(ws + 37748736);       // 4 MB  (2*INNER x DV)
  unsigned short* woutt = (unsigned short*)(ws + 41943040);      // 4 MB  (D x INNER)
  unsigned short* medb = (unsigned short*)(ws + 46137344);       // 4 MB  (B*J x DV)
  float* q = (float*)(ws + 50331648);                            // 33.5 MB (B*T x INNER)
  float* kv = (float*)(ws + 83886080);                           // 16.8 MB (B*J x 2*INNER)
  int* img_idx = (int*)(ws + 100663296);                         // 32 KB
  unsigned short* attn_out = xn;  // alias: xn dead after GEMM1

  scan_kernel<<<B_, 256, 0, stream>>>(mloc, img_idx);
  ln_kernel<<<B_ * T_, 256, 0, stream>>>(x, gamma, beta, xn);
  tcast<<<dim3(INNER_ / 32, D_ / 32), dim3(32, 8), 0, stream>>>(Wq, wqt, D_, INNER_);
  tcast<<<dim3(2 * INNER_ / 32, DV_ / 32), dim3(32, 8), 0, stream>>>(Wkv, wkvt, DV_, 2 * INNER_);
  tcast<<<dim3(D_ / 32, INNER_ / 32), dim3(32, 8), 0, stream>>>(Wout, woutt, INNER_, D_);
  cast_bf16<<<(B_ * J_ * DV_ / 4 + 255) / 256, 256, 0, stream>>>(media, medb, B_ * J_ * DV_ / 4);
  gemm_bt<<<(B_ * T_ / 128) * (INNER_ / 128), 256, 0, stream>>>(xn, wqt, q, B_ * T_, INNER_, D_);
  gemm_bt<<<(B_ * J_ / 128) * (2 * INNER_ / 128), 256, 0, stream>>>(medb, wkvt, kv, B_ * J_, 2 * INNER_, DV_);
  attn_kernel<<<B_ * T_ * H_ / 4, 256, 0, stream>>>(q, kv, img_idx, attn_out);
  gemm_bt<<<(B_ * T_ / 128) * (D_ / 128), 256, 0, stream>>>(attn_out, woutt, out, B_ * T_, D_, INNER_);
}

// Round 2
// 198.395 us; speedup vs baseline: 2.2851x; 2.2851x over previous
//
#include <hip/hip_runtime.h>
#include <hip/hip_bf16.h>

#define B_ 4
#define T_ 2048
#define D_ 2048
#define DV_ 1024
#define TIMG_ 8
#define NLAT_ 64
#define H_ 16
#define DH_ 64
#define INNER_ 1024
#define J_ (TIMG_ * NLAT_)  // 512

using f32x4 = __attribute__((ext_vector_type(4))) float;
using bf16x8 = __attribute__((ext_vector_type(8))) short;
using bf16x4 = __attribute__((ext_vector_type(4))) short;

__device__ __forceinline__ unsigned short f2bf(float f) {
  union { float f; unsigned int u; } c{f};
  unsigned int r = c.u + 0x7FFFu + ((c.u >> 16) & 1u);  // RNE
  return (unsigned short)(r >> 16);
}

// ---------------- media_locations scan -> img_idx (text_time-1) ----------------
__global__ __launch_bounds__(256) void scan_kernel(const void* __restrict__ locs,
                                                   int* __restrict__ img_idx) {
  __shared__ int sm[256];
  const int tid = threadIdx.x;
  const int b = blockIdx.x;
  const unsigned char* u8 = (const unsigned char*)locs;
  int cnt = 0;
  for (int i = tid; i < B_ * T_; i += 256) cnt += (u8[i] != 0) ? 1 : 0;
  sm[tid] = cnt;
  __syncthreads();
  for (int off = 128; off > 0; off >>= 1) {
    if (tid < off) sm[tid] += sm[tid + off];
    __syncthreads();
  }
  const bool u8mode = (sm[0] == B_ * TIMG_);
  __syncthreads();

  const int base = b * T_ + tid * 8;
  const int* i32 = (const int*)locs;
  int v[8];
  int ts = 0;
#pragma unroll
  for (int j = 0; j < 8; ++j) {
    v[j] = u8mode ? (u8[base + j] != 0 ? 1 : 0) : (i32[base + j] != 0 ? 1 : 0);
    ts += v[j];
  }
  sm[tid] = ts;
  __syncthreads();
  for (int off = 1; off < 256; off <<= 1) {
    int add = (tid >= off) ? sm[tid - off] : 0;
    __syncthreads();
    sm[tid] += add;
    __syncthreads();
  }
  int acc = sm[tid] - ts;  // exclusive prefix
#pragma unroll
  for (int j = 0; j < 8; ++j) {
    acc += v[j];
    img_idx[base + j] = acc - 1;  // -1 => no media yet
  }
}

// ---------------- LayerNorm (f32 in, bf16 out) ----------------
__global__ __launch_bounds__(256) void ln_kernel(const float* __restrict__ x,
                                                 const float* __restrict__ g,
                                                 const float* __restrict__ bta,
                                                 unsigned short* __restrict__ xn) {
  const int row = blockIdx.x;
  const int tid = threadIdx.x;
  const float4* xr = (const float4*)(x + (size_t)row * D_);
  float4 v0 = xr[tid];
  float4 v1 = xr[tid + 256];
  float s = v0.x + v0.y + v0.z + v0.w + v1.x + v1.y + v1.z + v1.w;
  float sq = v0.x * v0.x + v0.y * v0.y + v0.z * v0.z + v0.w * v0.w +
             v1.x * v1.x + v1.y * v1.y + v1.z * v1.z + v1.w * v1.w;
#pragma unroll
  for (int off = 32; off > 0; off >>= 1) {
    s += __shfl_xor(s, off);
    sq += __shfl_xor(sq, off);
  }
  __shared__ float ls[4], lq[4];
  const int lane = tid & 63, wave = tid >> 6;
  if (lane == 0) { ls[wave] = s; lq[wave] = sq; }
  __syncthreads();
  s = ls[0] + ls[1] + ls[2] + ls[3];
  sq = lq[0] + lq[1] + lq[2] + lq[3];
  const float mu = s * (1.0f / D_);
  const float rstd = rsqrtf(sq * (1.0f / D_) - mu * mu + 1e-5f);
  const float4* gv4 = (const float4*)g;
  const float4* bv4 = (const float4*)bta;
  ushort4* o4 = (ushort4*)(xn + (size_t)row * D_);
#pragma unroll
  for (int i = 0; i < 2; ++i) {
    const int idx = tid + i * 256;
    float4 vv = i == 0 ? v0 : v1;
    float4 gv = gv4[idx];
    float4 bv = bv4[idx];
    ushort4 o = make_ushort4(f2bf((vv.x - mu) * rstd * gv.x + bv.x),
                             f2bf((vv.y - mu) * rstd * gv.y + bv.y),
                             f2bf((vv.z - mu) * rstd * gv.z + bv.z),
                             f2bf((vv.w - mu) * rstd * gv.w + bv.w));
    o4[idx] = o;
  }
}

// ---------------- transpose + cast f32(RxC) -> bf16(CxR), with scale ----------------
__global__ void tcast(const float* __restrict__ in, unsigned short* __restrict__ out,
                      int R, int C, float scale) {
  __shared__ float tile[32][33];
  const int bc = blockIdx.x * 32;
  const int br = blockIdx.y * 32;
  const int tx = threadIdx.x, ty = threadIdx.y;
#pragma unroll
  for (int i = ty; i < 32; i += 8)
    tile[i][tx] = in[(size_t)(br + i) * C + bc + tx];
  __syncthreads();
#pragma unroll
  for (int i = ty; i < 32; i += 8)
    out[(size_t)(bc + i) * R + br + tx] = f2bf(tile[tx][i] * scale);
}

// ---------------- straight cast f32 -> bf16 (n4 float4 chunks) ----------------
__global__ void cast_bf16(const float* __restrict__ in, unsigned short* __restrict__ out,
                          int n4) {
  int i = blockIdx.x * blockDim.x + threadIdx.x;
  if (i >= n4) return;
  float4 v = ((const float4*)in)[i];
  ((ushort4*)out)[i] = make_ushort4(f2bf(v.x), f2bf(v.y), f2bf(v.z), f2bf(v.w));
}

// ---------------- bf16->bf16 transpose of V half of kv: vt[b][d][j] ----------------
__global__ void vtrans(const unsigned short* __restrict__ kvb, unsigned short* __restrict__ vt) {
  __shared__ unsigned short tile[32][33];
  const int jt = blockIdx.x * 32;
  const int dt = blockIdx.y * 32;
  const int b = blockIdx.z;
  const int tx = threadIdx.x, ty = threadIdx.y;
#pragma unroll
  for (int i = ty; i < 32; i += 8)
    tile[i][tx] = kvb[(size_t)(b * J_ + jt + i) * (2 * INNER_) + INNER_ + dt + tx];
  __syncthreads();
#pragma unroll
  for (int i = ty; i < 32; i += 8)
    vt[(size_t)(b * INNER_ + dt + i) * J_ + jt + tx] = tile[tx][i];
}

// ---------------- bf16 MFMA GEMM: C(MxN) = A(MxK) * BT(NxK)^T ----------------
template <bool BF16OUT>
__global__ __launch_bounds__(256) void gemm_bt(const unsigned short* __restrict__ A,
                                               const unsigned short* __restrict__ BT,
                                               void* __restrict__ Cv,
                                               int M, int N, int K) {
  __shared__ __align__(16) unsigned short As[128 * 64];
  __shared__ __align__(16) unsigned short Bs[128 * 64];
  const int tid = threadIdx.x;
  const int lane = tid & 63;
  const int wave = tid >> 6;
  const int gridN = N >> 7;
  const long row0 = (long)(blockIdx.x / gridN) << 7;
  const long col0 = (long)(blockIdx.x % gridN) << 7;
  const int wr = (wave >> 1) * 64;
  const int wc = (wave & 1) * 64;

  f32x4 acc[4][4] = {};

  for (int kt = 0; kt < K; kt += 64) {
    __syncthreads();
#pragma unroll
    for (int it = 0; it < 4; ++it) {
      const int ci = it * 256 + tid;
      const int r = ci >> 3;
      const int k8 = (ci & 7) << 3;
      const unsigned short* ga = A + (row0 + r) * K + kt + k8;
      const unsigned short* gb = BT + (col0 + r) * K + kt + k8;
      __builtin_amdgcn_global_load_lds(
          (const __attribute__((address_space(1))) unsigned int*)ga,
          (__attribute__((address_space(3))) unsigned int*)(As + ci * 8), 16, 0, 0);
      __builtin_amdgcn_global_load_lds(
          (const __attribute__((address_space(1))) unsigned int*)gb,
          (__attribute__((address_space(3))) unsigned int*)(Bs + ci * 8), 16, 0, 0);
    }
    asm volatile("s_waitcnt vmcnt(0)" ::: "memory");
    __syncthreads();
#pragma unroll
    for (int kk = 0; kk < 2; ++kk) {
      const int ko = kk * 32 + ((lane >> 4) << 3);
      const int ra = wr + (lane & 15);
      const int rb = wc + (lane & 15);
      bf16x8 af[4], bfr[4];
#pragma unroll
      for (int m = 0; m < 4; ++m)
        af[m] = *(const bf16x8*)(As + (ra + m * 16) * 64 + ko);
#pragma unroll
      for (int n = 0; n < 4; ++n)
        bfr[n] = *(const bf16x8*)(Bs + (rb + n * 16) * 64 + ko);
#pragma unroll
      for (int m = 0; m < 4; ++m)
#pragma unroll
        for (int n = 0; n < 4; ++n)
          acc[m][n] = __builtin_amdgcn_mfma_f32_16x16x32_bf16(af[m], bfr[n], acc[m][n], 0, 0, 0);
    }
  }
  const int cr = (lane >> 4) << 2;
  const int cc = lane & 15;
#pragma unroll
  for (int m = 0; m < 4; ++m)
#pragma unroll
    for (int n = 0; n < 4; ++n)
#pragma unroll
      for (int j = 0; j < 4; ++j) {
        const size_t idx = (row0 + wr + m * 16 + cr + j) * (size_t)N + col0 + wc + n * 16 + cc;
        if constexpr (BF16OUT)
          ((unsigned short*)Cv)[idx] = f2bf(acc[m][n][j]);
        else
          ((float*)Cv)[idx] = acc[m][n][j];
      }
}

// ---------------- MFMA masked cross-attention ----------------
// grid: B * (T/64) * 4 head-groups; one wave per head.
__global__ __launch_bounds__(256) void attn2_kernel(
    const unsigned short* __restrict__ qb,   // [B*T][INNER]  (scale folded into Wq)
    const unsigned short* __restrict__ kvb,  // [B*J][2*INNER]
    const unsigned short* __restrict__ vt,   // [B][INNER][J]
    const int* __restrict__ img_idx,         // [B*T]
    unsigned short* __restrict__ attn_out) { // [B*T][INNER]
  __shared__ unsigned short Pl[4][64 * 72];
  const int tid = threadIdx.x;
  const int lane = tid & 63;
  const int w = tid >> 6;
  int bid = blockIdx.x;
  const int hg = bid & 3; bid >>= 2;
  const int tile = bid & 31; bid >>= 5;
  const int b = bid;
  const int t0 = tile * 64;
  const int h = hg * 4 + w;
  const int l15 = lane & 15;
  const int lg = lane >> 4;  // 0..3

  const int* ii = img_idx + b * T_ + t0;
  int myimg = ii[lane];
  int tmin = myimg, tmax = myimg;
#pragma unroll
  for (int off = 1; off < 64; off <<= 1) {
    tmin = min(tmin, __shfl_xor(tmin, off));
    tmax = max(tmax, __shfl_xor(tmax, off));
  }
  unsigned short* op = attn_out + (size_t)(b * T_ + t0) * INNER_ + h * DH_;
  if (tmin < 0) {
    for (int r = 0; r < 64; ++r)
      if (ii[r] < 0) op[(size_t)r * INNER_ + lane] = 0;
  }
  if (tmax < 0) return;

  // Q fragments (held across image passes)
  bf16x8 qa[4][2];
  const unsigned short* qrow = qb + (size_t)(b * T_ + t0) * INNER_ + h * DH_;
#pragma unroll
  for (int m = 0; m < 4; ++m)
#pragma unroll
    for (int kk = 0; kk < 2; ++kk)
      qa[m][kk] = *(const bf16x8*)(qrow + (size_t)(l15 + m * 16) * INNER_ + kk * 32 + lg * 8);

  unsigned short* pw = Pl[w];
  for (int img = max(tmin, 0); img <= tmax; ++img) {
    // ---- S = Q K^T (K rows are B^T layout [key][d]) ----
    const unsigned short* Kb = kvb + (size_t)(b * J_ + img * NLAT_) * (2 * INNER_) + h * DH_;
    f32x4 acc[4][4] = {};
#pragma unroll
    for (int kk = 0; kk < 2; ++kk) {
      bf16x8 bfr[4];
#pragma unroll
      for (int n = 0; n < 4; ++n)
        bfr[n] = *(const bf16x8*)(Kb + (size_t)(l15 + n * 16) * (2 * INNER_) + kk * 32 + lg * 8);
#pragma unroll
      for (int m = 0; m < 4; ++m)
#pragma unroll
        for (int n = 0; n < 4; ++n)
          acc[m][n] = __builtin_amdgcn_mfma_f32_16x16x32_bf16(qa[m][kk], bfr[n], acc[m][n], 0, 0, 0);
    }
    // ---- wave-parallel softmax over 64 keys per row; write normalized P to LDS ----
#pragma unroll
    for (int m = 0; m < 4; ++m) {
#pragma unroll
      for (int j = 0; j < 4; ++j) {
        float mx = fmaxf(fmaxf(acc[m][0][j], acc[m][1][j]), fmaxf(acc[m][2][j], acc[m][3][j]));
#pragma unroll
        for (int off = 1; off < 16; off <<= 1) mx = fmaxf(mx, __shfl_xor(mx, off));
        float sum = 0.f;
#pragma unroll
        for (int n = 0; n < 4; ++n) {
          float e = __expf(acc[m][n][j] - mx);
          acc[m][n][j] = e;
          sum += e;
        }
#pragma unroll
        for (int off = 1; off < 16; off <<= 1) sum += __shfl_xor(sum, off);
        const float ri = 1.0f / sum;
        const int row = m * 16 + lg * 4 + j;
#pragma unroll
        for (int n = 0; n < 4; ++n)
          pw[row * 72 + n * 16 + l15] = f2bf(acc[m][n][j] * ri);
      }
    }
    // ---- O = P V  (V^T rows come from vt [d][key]) ----
    const unsigned short* Vb = vt + (size_t)(b * INNER_ + h * DH_) * J_ + img * NLAT_;
    f32x4 oacc[4][4] = {};
#pragma unroll
    for (int kk = 0; kk < 2; ++kk) {
      bf16x8 pa[4], bfr[4];
#pragma unroll
      for (int m = 0; m < 4; ++m) {
        // stride-72 rows: 8B-aligned -> two bf16x4 LDS reads, bank-conflict-free
        bf16x4 lo = *(const bf16x4*)(pw + (m * 16 + l15) * 72 + kk * 32 + lg * 8);
        bf16x4 hi = *(const bf16x4*)(pw + (m * 16 + l15) * 72 + kk * 32 + lg * 8 + 4);
        bf16x8 v;
#pragma unroll
        for (int e = 0; e < 4; ++e) { v[e] = lo[e]; v[e + 4] = hi[e]; }
        pa[m] = v;
      }
#pragma unroll
      for (int n = 0; n < 4; ++n)
        bfr[n] = *(const bf16x8*)(Vb + (size_t)(l15 + n * 16) * J_ + kk * 32 + lg * 8);
#pragma unroll
      for (int m = 0; m < 4; ++m)
#pragma unroll
        for (int n = 0; n < 4; ++n)
          oacc[m][n] = __builtin_amdgcn_mfma_f32_16x16x32_bf16(pa[m], bfr[n], oacc[m][n], 0, 0, 0);
    }
    // ---- masked write ----
#pragma unroll
    for (int m = 0; m < 4; ++m)
#pragma unroll
      for (int j = 0; j < 4; ++j) {
        const int row = m * 16 + lg * 4 + j;
        if (ii[row] == img) {
#pragma unroll
          for (int n = 0; n < 4; ++n)
            op[(size_t)row * INNER_ + n * 16 + l15] = f2bf(oacc[m][n][j]);
        }
      }
  }
}

extern "C" void kernel_launch(void* const* d_in, const int* in_sizes, int n_in,
                              void* d_out, int out_size, void* d_ws, size_t ws_size,
                              hipStream_t stream) {
  const float* x = (const float*)d_in[0];
  const float* media = (const float*)d_in[1];
  const void* mloc = d_in[2];
  const float* gamma = (const float*)d_in[3];
  const float* beta = (const float*)d_in[4];
  const float* Wq = (const float*)d_in[5];
  const float* Wkv = (const float*)d_in[6];
  const float* Wout = (const float*)d_in[7];
  float* out = (float*)d_out;

  char* ws = (char*)d_ws;
  unsigned short* xn = (unsigned short*)(ws);                  // 33.5 MB (aliased attn_out)
  unsigned short* wqt = (unsigned short*)(ws + 33554432);      // 4 MB (INNER x D, scale folded)
  unsigned short* wkvt = (unsigned short*)(ws + 37748736);     // 4 MB (2*INNER x DV)
  unsigned short* woutt = (unsigned short*)(ws + 41943040);    // 4 MB (D x INNER)
  unsigned short* medb = (unsigned short*)(ws + 46137344);     // 4.2 MB (B*J x DV)
  unsigned short* qb = (unsigned short*)(ws + 50331648);       // 16.8 MB (B*T x INNER, bf16)
  unsigned short* kvb = (unsigned short*)(ws + 67108864);      // 8.4 MB (B*J x 2*INNER, bf16)
  unsigned short* vt = (unsigned short*)(ws + 75497472);       // 4.2 MB (B x INNER x J, bf16)
  int* img_idx = (int*)(ws + 79691776);                        // 32 KB
  unsigned short* attn_out = xn;  // xn dead after GEMM1

  scan_kernel<<<B_, 256, 0, stream>>>(mloc, img_idx);
  ln_kernel<<<B_ * T_, 256, 0, stream>>>(x, gamma, beta, xn);
  tcast<<<dim3(INNER_ / 32, D_ / 32), dim3(32, 8), 0, stream>>>(Wq, wqt, D_, INNER_, 0.125f);
  tcast<<<dim3(2 * INNER_ / 32, DV_ / 32), dim3(32, 8), 0, stream>>>(Wkv, wkvt, DV_, 2 * INNER_, 1.0f);
  tcast<<<dim3(D_ / 32, INNER_ / 32), dim3(32, 8), 0, stream>>>(Wout, woutt, INNER_, D_, 1.0f);
  cast_bf16<<<(B_ * J_ * DV_ / 4 + 255) / 256, 256, 0, stream>>>(media, medb, B_ * J_ * DV_ / 4);
  gemm_bt<true><<<(B_ * T_ / 128) * (INNER_ / 128), 256, 0, stream>>>(xn, wqt, qb, B_ * T_, INNER_, D_);
  gemm_bt<true><<<(B_ * J_ / 128) * (2 * INNER_ / 128), 256, 0, stream>>>(medb, wkvt, kvb, B_ * J_, 2 * INNER_, DV_);
  vtrans<<<dim3(J_ / 32, INNER_ / 32, B_), dim3(32, 8), 0, stream>>>(kvb, vt);
  attn2_kernel<<<B_ * (T_ / 64) * 4, 256, 0, stream>>>(qb, kvb, vt, img_idx, attn_out);
  gemm_bt<false><<<(B_ * T_ / 128) * (D_ / 128), 256, 0, stream>>>(attn_out, woutt, out, B_ * T_, D_, INNER_);
}

// Round 3
// 173.858 us; speedup vs baseline: 2.6076x; 1.1411x over previous
//
#include <hip/hip_runtime.h>
#include <hip/hip_bf16.h>

#define B_ 4
#define T_ 2048
#define D_ 2048
#define DV_ 1024
#define TIMG_ 8
#define NLAT_ 64
#define H_ 16
#define DH_ 64
#define INNER_ 1024
#define J_ (TIMG_ * NLAT_)  // 512

using f32x4 = __attribute__((ext_vector_type(4))) float;
using bf16x8 = __attribute__((ext_vector_type(8))) short;
using bf16x4 = __attribute__((ext_vector_type(4))) short;

__device__ __forceinline__ unsigned short f2bf(float f) {
  union { float f; unsigned int u; } c{f};
  unsigned int r = c.u + 0x7FFFu + ((c.u >> 16) & 1u);  // RNE
  return (unsigned short)(r >> 16);
}

__device__ __forceinline__ void stage16(const unsigned short* g, unsigned short* l) {
  __builtin_amdgcn_global_load_lds(
      (const __attribute__((address_space(1))) unsigned int*)g,
      (__attribute__((address_space(3))) unsigned int*)l, 16, 0, 0);
}

// ---------------- media_locations scan -> img_idx (text_time-1) ----------------
__global__ __launch_bounds__(256) void scan_kernel(const void* __restrict__ locs,
                                                   int* __restrict__ img_idx) {
  __shared__ int sm[256];
  const int tid = threadIdx.x;
  const int b = blockIdx.x;
  const unsigned char* u8 = (const unsigned char*)locs;
  int cnt = 0;
  for (int i = tid; i < B_ * T_; i += 256) cnt += (u8[i] != 0) ? 1 : 0;
  sm[tid] = cnt;
  __syncthreads();
  for (int off = 128; off > 0; off >>= 1) {
    if (tid < off) sm[tid] += sm[tid + off];
    __syncthreads();
  }
  const bool u8mode = (sm[0] == B_ * TIMG_);
  __syncthreads();

  const int base = b * T_ + tid * 8;
  const int* i32 = (const int*)locs;
  int v[8];
  int ts = 0;
#pragma unroll
  for (int j = 0; j < 8; ++j) {
    v[j] = u8mode ? (u8[base + j] != 0 ? 1 : 0) : (i32[base + j] != 0 ? 1 : 0);
    ts += v[j];
  }
  sm[tid] = ts;
  __syncthreads();
  for (int off = 1; off < 256; off <<= 1) {
    int add = (tid >= off) ? sm[tid - off] : 0;
    __syncthreads();
    sm[tid] += add;
    __syncthreads();
  }
  int acc = sm[tid] - ts;  // exclusive prefix
#pragma unroll
  for (int j = 0; j < 8; ++j) {
    acc += v[j];
    img_idx[base + j] = acc - 1;  // -1 => no media yet
  }
}

// ---------------- LayerNorm (f32 in, bf16 out) ----------------
__global__ __launch_bounds__(256) void ln_kernel(const float* __restrict__ x,
                                                 const float* __restrict__ g,
                                                 const float* __restrict__ bta,
                                                 unsigned short* __restrict__ xn) {
  const int row = blockIdx.x;
  const int tid = threadIdx.x;
  const float4* xr = (const float4*)(x + (size_t)row * D_);
  float4 v0 = xr[tid];
  float4 v1 = xr[tid + 256];
  float s = v0.x + v0.y + v0.z + v0.w + v1.x + v1.y + v1.z + v1.w;
  float sq = v0.x * v0.x + v0.y * v0.y + v0.z * v0.z + v0.w * v0.w +
             v1.x * v1.x + v1.y * v1.y + v1.z * v1.z + v1.w * v1.w;
#pragma unroll
  for (int off = 32; off > 0; off >>= 1) {
    s += __shfl_xor(s, off);
    sq += __shfl_xor(sq, off);
  }
  __shared__ float ls[4], lq[4];
  const int lane = tid & 63, wave = tid >> 6;
  if (lane == 0) { ls[wave] = s; lq[wave] = sq; }
  __syncthreads();
  s = ls[0] + ls[1] + ls[2] + ls[3];
  sq = lq[0] + lq[1] + lq[2] + lq[3];
  const float mu = s * (1.0f / D_);
  const float rstd = rsqrtf(sq * (1.0f / D_) - mu * mu + 1e-5f);
  const float4* gv4 = (const float4*)g;
  const float4* bv4 = (const float4*)bta;
  ushort4* o4 = (ushort4*)(xn + (size_t)row * D_);
#pragma unroll
  for (int i = 0; i < 2; ++i) {
    const int idx = tid + i * 256;
    float4 vv = i == 0 ? v0 : v1;
    float4 gv = gv4[idx];
    float4 bv = bv4[idx];
    ushort4 o = make_ushort4(f2bf((vv.x - mu) * rstd * gv.x + bv.x),
                             f2bf((vv.y - mu) * rstd * gv.y + bv.y),
                             f2bf((vv.z - mu) * rstd * gv.z + bv.z),
                             f2bf((vv.w - mu) * rstd * gv.w + bv.w));
    o4[idx] = o;
  }
}

// ---------------- transpose + cast f32(RxC) -> bf16(CxR), with scale ----------------
__global__ void tcast(const float* __restrict__ in, unsigned short* __restrict__ out,
                      int R, int C, float scale) {
  __shared__ float tile[32][33];
  const int bc = blockIdx.x * 32;
  const int br = blockIdx.y * 32;
  const int tx = threadIdx.x, ty = threadIdx.y;
#pragma unroll
  for (int i = ty; i < 32; i += 8)
    tile[i][tx] = in[(size_t)(br + i) * C + bc + tx];
  __syncthreads();
#pragma unroll
  for (int i = ty; i < 32; i += 8)
    out[(size_t)(bc + i) * R + br + tx] = f2bf(tile[tx][i] * scale);
}

// ---------------- straight cast f32 -> bf16 (n4 float4 chunks) ----------------
__global__ void cast_bf16(const float* __restrict__ in, unsigned short* __restrict__ out,
                          int n4) {
  int i = blockIdx.x * blockDim.x + threadIdx.x;
  if (i >= n4) return;
  float4 v = ((const float4*)in)[i];
  ((ushort4*)out)[i] = make_ushort4(f2bf(v.x), f2bf(v.y), f2bf(v.z), f2bf(v.w));
}

// ---------------- bf16->bf16 transpose of V half of kv: vt[b][d][j] ----------------
__global__ void vtrans(const unsigned short* __restrict__ kvb, unsigned short* __restrict__ vt) {
  __shared__ unsigned short tile[32][33];
  const int jt = blockIdx.x * 32;
  const int dt = blockIdx.y * 32;
  const int b = blockIdx.z;
  const int tx = threadIdx.x, ty = threadIdx.y;
#pragma unroll
  for (int i = ty; i < 32; i += 8)
    tile[i][tx] = kvb[(size_t)(b * J_ + jt + i) * (2 * INNER_) + INNER_ + dt + tx];
  __syncthreads();
#pragma unroll
  for (int i = ty; i < 32; i += 8)
    vt[(size_t)(b * INNER_ + dt + i) * J_ + jt + tx] = tile[tx][i];
}

// ============ 8-wave 2-phase pipelined MFMA GEMM: C(MxN) = A(MxK) * BT(NxK)^T ============
// BM=128, BN=256, BK=64. 8 waves = 2M x 4N, per-wave 64x64 output.
// LDS per buffer: A 128x64 (16KB, shorts 0..8191) + B 256x64 (32KB, shorts 8192..24575).
// XOR swizzle: 16B-slot index ^= (row&7); applied to global SOURCE at stage time
// (global_load_lds writes linearly) and to ds_read addresses (rule #21: both sides).
// Phase 1 reads A(all m) + B rows 0..127 (n=0,1); Phase 2 reads B rows 128..255.
// Stage schedule (tile granularity, 6 loads = A0,A1,Bt0,Bt1,Bb0,Bb1):
//   Ph1(t): stage Bbot(t+1) -> buf^1  (region last read Ph2(t-1), 2 barriers upstream)
//   Ph2(t): stage A+Btop(t+2) -> buf  (region last read Ph1(t),   2 barriers upstream)
// vmcnt(6) every phase: leaves exactly the younger-stage loads in flight, waits the
// region needed by the NEXT phase (counted-vmcnt, never drain-0 in the loop).
template <bool BF16OUT>
__global__ __launch_bounds__(512, 2) void gemm_8ph(const unsigned short* __restrict__ Ag,
                                                   const unsigned short* __restrict__ Bg,
                                                   void* __restrict__ Cv,
                                                   int M, int N, int K) {
  __shared__ __align__(16) unsigned short lds[2][24576];
  const int tid = threadIdx.x;
  const int lane = tid & 63;
  const int wave = tid >> 6;
  const int l15 = lane & 15;
  const int lg8 = (lane >> 4) << 3;  // 0,8,16,24 shorts
  const int wr64 = (wave >> 2) << 6; // 0 or 64
  const int wc16 = (wave & 3) << 4;  // 0,16,32,48

  // bijective XCD swizzle (grid % 8 == 0 for all our shapes), column-major tile map
  const int nwg = gridDim.x;
  int wg = ((int)blockIdx.x & 7) * (nwg >> 3) + ((int)blockIdx.x >> 3);
  const int gridM = M >> 7;
  const long row0 = (long)(wg % gridM) << 7;
  const long col0 = (long)(wg / gridM) << 8;

  auto stageA = [&](int buf, int kt, int r) {
    const int i = r * 512 + tid;
    const int row = i >> 3;
    const int c = (i & 7) ^ (row & 7);
    stage16(Ag + (size_t)(row0 + row) * K + kt + c * 8, &lds[buf][i * 8]);
  };
  auto stageB = [&](int buf, int kt, int r) {  // r in 0..3; 0,1=Btop 2,3=Bbot
    const int i = r * 512 + tid;
    const int row = i >> 3;
    const int c = (i & 7) ^ (row & 7);
    stage16(Bg + (size_t)(col0 + row) * K + kt + c * 8, &lds[buf][8192 + i * 8]);
  };

  const int NT = K >> 6;
  // prologue: full-stage t0 -> buf0, t1 -> buf1 (order: A0,A1,Bt0,Bt1,Bb0,Bb1)
  stageA(0, 0, 0); stageA(0, 0, 1);
  stageB(0, 0, 0); stageB(0, 0, 1); stageB(0, 0, 2); stageB(0, 0, 3);
  stageA(1, 64, 0); stageA(1, 64, 1);
  stageB(1, 64, 0); stageB(1, 64, 1); stageB(1, 64, 2); stageB(1, 64, 3);
  asm volatile("s_waitcnt vmcnt(6)" ::: "memory");  // t0 landed
  asm volatile("s_barrier" ::: "memory");

  f32x4 acc[4][4] = {};
  int cur = 0;
  for (int t = 0; t < NT; ++t, cur ^= 1) {
    const unsigned short* Ab = &lds[cur][0];
    const unsigned short* Bb = &lds[cur][8192];
    bf16x8 af[4][2], bfr[4][2];
    // ---------- Phase 1: read A(all) + Btop; MFMA n=0,1 ----------
#pragma unroll
    for (int m = 0; m < 4; ++m)
#pragma unroll
      for (int kk = 0; kk < 2; ++kk) {
        const int row = wr64 + m * 16 + l15;
        af[m][kk] = *(const bf16x8*)(Ab + row * 64 + ((kk * 32 + lg8) ^ ((row & 7) << 3)));
      }
#pragma unroll
    for (int n = 0; n < 2; ++n)
#pragma unroll
      for (int kk = 0; kk < 2; ++kk) {
        const int brow = n * 64 + wc16 + l15;
        bfr[n][kk] = *(const bf16x8*)(Bb + brow * 64 + ((kk * 32 + lg8) ^ ((brow & 7) << 3)));
      }
    if (t >= 1 && t + 1 < NT) {
      stageB(cur ^ 1, (t + 1) << 6, 2); stageB(cur ^ 1, (t + 1) << 6, 3);
    }
    asm volatile("s_waitcnt vmcnt(6)" ::: "memory");
    asm volatile("s_barrier" ::: "memory");
    asm volatile("s_waitcnt lgkmcnt(0)" ::: "memory");
    __builtin_amdgcn_s_setprio(1);
#pragma unroll
    for (int m = 0; m < 4; ++m)
#pragma unroll
      for (int n = 0; n < 2; ++n)
#pragma unroll
        for (int kk = 0; kk < 2; ++kk)
          acc[m][n] = __builtin_amdgcn_mfma_f32_16x16x32_bf16(af[m][kk], bfr[n][kk], acc[m][n], 0, 0, 0);
    __builtin_amdgcn_s_setprio(0);
    asm volatile("s_barrier" ::: "memory");
    // ---------- Phase 2: read Bbot; MFMA n=2,3 ----------
#pragma unroll
    for (int n = 2; n < 4; ++n)
#pragma unroll
      for (int kk = 0; kk < 2; ++kk) {
        const int brow = n * 64 + wc16 + l15;
        bfr[n][kk] = *(const bf16x8*)(Bb + brow * 64 + ((kk * 32 + lg8) ^ ((brow & 7) << 3)));
      }
    if (t + 2 < NT) {
      stageA(cur, (t + 2) << 6, 0); stageA(cur, (t + 2) << 6, 1);
      stageB(cur, (t + 2) << 6, 0); stageB(cur, (t + 2) << 6, 1);
    }
    asm volatile("s_waitcnt vmcnt(6)" ::: "memory");
    asm volatile("s_barrier" ::: "memory");
    asm volatile("s_waitcnt lgkmcnt(0)" ::: "memory");
    __builtin_amdgcn_s_setprio(1);
#pragma unroll
    for (int m = 0; m < 4; ++m)
#pragma unroll
      for (int n = 2; n < 4; ++n)
#pragma unroll
        for (int kk = 0; kk < 2; ++kk)
          acc[m][n] = __builtin_amdgcn_mfma_f32_16x16x32_bf16(af[m][kk], bfr[n][kk], acc[m][n], 0, 0, 0);
    __builtin_amdgcn_s_setprio(0);
    asm volatile("s_barrier" ::: "memory");
  }

  // epilogue: C/D layout col=lane&15, row=(lane>>4)*4+j
  const int cr = (lane >> 4) << 2;
#pragma unroll
  for (int m = 0; m < 4; ++m)
#pragma unroll
    for (int n = 0; n < 4; ++n)
#pragma unroll
      for (int j = 0; j < 4; ++j) {
        const size_t idx = (row0 + wr64 + m * 16 + cr + j) * (size_t)N + col0 + n * 64 + wc16 + l15;
        if constexpr (BF16OUT)
          ((unsigned short*)Cv)[idx] = f2bf(acc[m][n][j]);
        else
          ((float*)Cv)[idx] = acc[m][n][j];
      }
}

// ---------------- MFMA masked cross-attention ----------------
// grid: B * (T/64) * 4 head-groups; one wave per head.
__global__ __launch_bounds__(256) void attn2_kernel(
    const unsigned short* __restrict__ qb,   // [B*T][INNER]  (scale folded into Wq)
    const unsigned short* __restrict__ kvb,  // [B*J][2*INNER]
    const unsigned short* __restrict__ vt,   // [B][INNER][J]
    const int* __restrict__ img_idx,         // [B*T]
    unsigned short* __restrict__ attn_out) { // [B*T][INNER]
  __shared__ unsigned short Pl[4][64 * 72];
  const int tid = threadIdx.x;
  const int lane = tid & 63;
  const int w = tid >> 6;
  int bid = blockIdx.x;
  const int hg = bid & 3; bid >>= 2;
  const int tile = bid & 31; bid >>= 5;
  const int b = bid;
  const int t0 = tile * 64;
  const int h = hg * 4 + w;
  const int l15 = lane & 15;
  const int lg = lane >> 4;  // 0..3

  const int* ii = img_idx + b * T_ + t0;
  int myimg = ii[lane];
  int tmin = myimg, tmax = myimg;
#pragma unroll
  for (int off = 1; off < 64; off <<= 1) {
    tmin = min(tmin, __shfl_xor(tmin, off));
    tmax = max(tmax, __shfl_xor(tmax, off));
  }
  unsigned short* op = attn_out + (size_t)(b * T_ + t0) * INNER_ + h * DH_;
  if (tmin < 0) {
    for (int r = 0; r < 64; ++r)
      if (ii[r] < 0) op[(size_t)r * INNER_ + lane] = 0;
  }
  if (tmax < 0) return;

  // Q fragments (held across image passes)
  bf16x8 qa[4][2];
  const unsigned short* qrow = qb + (size_t)(b * T_ + t0) * INNER_ + h * DH_;
#pragma unroll
  for (int m = 0; m < 4; ++m)
#pragma unroll
    for (int kk = 0; kk < 2; ++kk)
      qa[m][kk] = *(const bf16x8*)(qrow + (size_t)(l15 + m * 16) * INNER_ + kk * 32 + lg * 8);

  unsigned short* pw = Pl[w];
  for (int img = max(tmin, 0); img <= tmax; ++img) {
    // ---- S = Q K^T (K rows are B^T layout [key][d]) ----
    const unsigned short* Kb = kvb + (size_t)(b * J_ + img * NLAT_) * (2 * INNER_) + h * DH_;
    f32x4 acc[4][4] = {};
#pragma unroll
    for (int kk = 0; kk < 2; ++kk) {
      bf16x8 bfr[4];
#pragma unroll
      for (int n = 0; n < 4; ++n)
        bfr[n] = *(const bf16x8*)(Kb + (size_t)(l15 + n * 16) * (2 * INNER_) + kk * 32 + lg * 8);
#pragma unroll
      for (int m = 0; m < 4; ++m)
#pragma unroll
        for (int n = 0; n < 4; ++n)
          acc[m][n] = __builtin_amdgcn_mfma_f32_16x16x32_bf16(qa[m][kk], bfr[n], acc[m][n], 0, 0, 0);
    }
    // ---- wave-parallel softmax over 64 keys per row; write normalized P to LDS ----
#pragma unroll
    for (int m = 0; m < 4; ++m) {
#pragma unroll
      for (int j = 0; j < 4; ++j) {
        float mx = fmaxf(fmaxf(acc[m][0][j], acc[m][1][j]), fmaxf(acc[m][2][j], acc[m][3][j]));
#pragma unroll
        for (int off = 1; off < 16; off <<= 1) mx = fmaxf(mx, __shfl_xor(mx, off));
        float sum = 0.f;
#pragma unroll
        for (int n = 0; n < 4; ++n) {
          float e = __expf(acc[m][n][j] - mx);
          acc[m][n][j] = e;
          sum += e;
        }
#pragma unroll
        for (int off = 1; off < 16; off <<= 1) sum += __shfl_xor(sum, off);
        const float ri = 1.0f / sum;
        const int row = m * 16 + lg * 4 + j;
#pragma unroll
        for (int n = 0; n < 4; ++n)
          pw[row * 72 + n * 16 + l15] = f2bf(acc[m][n][j] * ri);
      }
    }
    // ---- O = P V  (V^T rows come from vt [d][key]) ----
    const unsigned short* Vb = vt + (size_t)(b * INNER_ + h * DH_) * J_ + img * NLAT_;
    f32x4 oacc[4][4] = {};
#pragma unroll
    for (int kk = 0; kk < 2; ++kk) {
      bf16x8 pa[4], bfr[4];
#pragma unroll
      for (int m = 0; m < 4; ++m) {
        bf16x4 lo = *(const bf16x4*)(pw + (m * 16 + l15) * 72 + kk * 32 + lg * 8);
        bf16x4 hi = *(const bf16x4*)(pw + (m * 16 + l15) * 72 + kk * 32 + lg * 8 + 4);
        bf16x8 v;
#pragma unroll
        for (int e = 0; e < 4; ++e) { v[e] = lo[e]; v[e + 4] = hi[e]; }
        pa[m] = v;
      }
#pragma unroll
      for (int n = 0; n < 4; ++n)
        bfr[n] = *(const bf16x8*)(Vb + (size_t)(l15 + n * 16) * J_ + kk * 32 + lg * 8);
#pragma unroll
      for (int m = 0; m < 4; ++m)
#pragma unroll
        for (int n = 0; n < 4; ++n)
          oacc[m][n] = __builtin_amdgcn_mfma_f32_16x16x32_bf16(pa[m], bfr[n], oacc[m][n], 0, 0, 0);
    }
    // ---- masked write ----
#pragma unroll
    for (int m = 0; m < 4; ++m)
#pragma unroll
      for (int j = 0; j < 4; ++j) {
        const int row = m * 16 + lg * 4 + j;
        if (ii[row] == img) {
#pragma unroll
          for (int n = 0; n < 4; ++n)
            op[(size_t)row * INNER_ + n * 16 + l15] = f2bf(oacc[m][n][j]);
        }
      }
  }
}

extern "C" void kernel_launch(void* const* d_in, const int* in_sizes, int n_in,
                              void* d_out, int out_size, void* d_ws, size_t ws_size,
                              hipStream_t stream) {
  const float* x = (const float*)d_in[0];
  const float* media = (const float*)d_in[1];
  const void* mloc = d_in[2];
  const float* gamma = (const float*)d_in[3];
  const float* beta = (const float*)d_in[4];
  const float* Wq = (const float*)d_in[5];
  const float* Wkv = (const float*)d_in[6];
  const float* Wout = (const float*)d_in[7];
  float* out = (float*)d_out;

  char* ws = (char*)d_ws;
  unsigned short* xn = (unsigned short*)(ws);                  // 33.5 MB (aliased attn_out)
  unsigned short* wqt = (unsigned short*)(ws + 33554432);      // 4 MB (INNER x D, scale folded)
  unsigned short* wkvt = (unsigned short*)(ws + 37748736);     // 4 MB (2*INNER x DV)
  unsigned short* woutt = (unsigned short*)(ws + 41943040);    // 4 MB (D x INNER)
  unsigned short* medb = (unsigned short*)(ws + 46137344);     // 4.2 MB (B*J x DV)
  unsigned short* qb = (unsigned short*)(ws + 50331648);       // 16.8 MB (B*T x INNER, bf16)
  unsigned short* kvb = (unsigned short*)(ws + 67108864);      // 8.4 MB (B*J x 2*INNER, bf16)
  unsigned short* vt = (unsigned short*)(ws + 75497472);       // 4.2 MB (B x INNER x J, bf16)
  int* img_idx = (int*)(ws + 79691776);                        // 32 KB
  unsigned short* attn_out = xn;  // xn dead after GEMM1

  scan_kernel<<<B_, 256, 0, stream>>>(mloc, img_idx);
  ln_kernel<<<B_ * T_, 256, 0, stream>>>(x, gamma, beta, xn);
  tcast<<<dim3(INNER_ / 32, D_ / 32), dim3(32, 8), 0, stream>>>(Wq, wqt, D_, INNER_, 0.125f);
  tcast<<<dim3(2 * INNER_ / 32, DV_ / 32), dim3(32, 8), 0, stream>>>(Wkv, wkvt, DV_, 2 * INNER_, 1.0f);
  tcast<<<dim3(D_ / 32, INNER_ / 32), dim3(32, 8), 0, stream>>>(Wout, woutt, INNER_, D_, 1.0f);
  cast_bf16<<<(B_ * J_ * DV_ / 4 + 255) / 256, 256, 0, stream>>>(media, medb, B_ * J_ * DV_ / 4);
  // GEMM1: q = xn @ Wq^T' (M=8192,N=1024,K=2048) -> 256 blocks
  gemm_8ph<true><<<(B_ * T_ / 128) * (INNER_ / 256), 512, 0, stream>>>(xn, wqt, qb, B_ * T_, INNER_, D_);
  // GEMM2: kv = media @ Wkv (M=2048,N=2048,K=1024) -> 128 blocks
  gemm_8ph<true><<<(B_ * J_ / 128) * (2 * INNER_ / 256), 512, 0, stream>>>(medb, wkvt, kvb, B_ * J_, 2 * INNER_, DV_);
  vtrans<<<dim3(J_ / 32, INNER_ / 32, B_), dim3(32, 8), 0, stream>>>(kvb, vt);
  attn2_kernel<<<B_ * (T_ / 64) * 4, 256, 0, stream>>>(qb, kvb, vt, img_idx, attn_out);
  // GEMM3: out = attn_out @ Wout (M=8192,N=2048,K=1024) -> 512 blocks
  gemm_8ph<false><<<(B_ * T_ / 128) * (D_ / 256), 512, 0, stream>>>(attn_out, woutt, out, B_ * T_, D_, INNER_);
}

// Round 4
// 164.600 us; speedup vs baseline: 2.7543x; 1.0562x over previous
//
#include <hip/hip_runtime.h>
#include <hip/hip_bf16.h>

#define B_ 4
#define T_ 2048
#define D_ 2048
#define DV_ 1024
#define TIMG_ 8
#define NLAT_ 64
#define H_ 16
#define DH_ 64
#define INNER_ 1024
#define J_ (TIMG_ * NLAT_)  // 512

using f32x4 = __attribute__((ext_vector_type(4))) float;
using bf16x8 = __attribute__((ext_vector_type(8))) short;
using bf16x4 = __attribute__((ext_vector_type(4))) short;

__device__ __forceinline__ unsigned short f2bf(float f) {
  union { float f; unsigned int u; } c{f};
  unsigned int r = c.u + 0x7FFFu + ((c.u >> 16) & 1u);  // RNE
  return (unsigned short)(r >> 16);
}

__device__ __forceinline__ void stage16(const unsigned short* g, unsigned short* l) {
  __builtin_amdgcn_global_load_lds(
      (const __attribute__((address_space(1))) unsigned int*)g,
      (__attribute__((address_space(3))) unsigned int*)l, 16, 0, 0);
}

// ---------------- media_locations scan -> img_idx (text_time-1) ----------------
__global__ __launch_bounds__(256) void scan_kernel(const void* __restrict__ locs,
                                                   int* __restrict__ img_idx) {
  __shared__ int sm[256];
  const int tid = threadIdx.x;
  const int b = blockIdx.x;
  const unsigned char* u8 = (const unsigned char*)locs;
  int cnt = 0;
  for (int i = tid; i < B_ * T_; i += 256) cnt += (u8[i] != 0) ? 1 : 0;
  sm[tid] = cnt;
  __syncthreads();
  for (int off = 128; off > 0; off >>= 1) {
    if (tid < off) sm[tid] += sm[tid + off];
    __syncthreads();
  }
  const bool u8mode = (sm[0] == B_ * TIMG_);
  __syncthreads();

  const int base = b * T_ + tid * 8;
  const int* i32 = (const int*)locs;
  int v[8];
  int ts = 0;
#pragma unroll
  for (int j = 0; j < 8; ++j) {
    v[j] = u8mode ? (u8[base + j] != 0 ? 1 : 0) : (i32[base + j] != 0 ? 1 : 0);
    ts += v[j];
  }
  sm[tid] = ts;
  __syncthreads();
  for (int off = 1; off < 256; off <<= 1) {
    int add = (tid >= off) ? sm[tid - off] : 0;
    __syncthreads();
    sm[tid] += add;
    __syncthreads();
  }
  int acc = sm[tid] - ts;  // exclusive prefix
#pragma unroll
  for (int j = 0; j < 8; ++j) {
    acc += v[j];
    img_idx[base + j] = acc - 1;  // -1 => no media yet
  }
}

// ---------------- LayerNorm (f32 in, bf16 out) ----------------
__global__ __launch_bounds__(256) void ln_kernel(const float* __restrict__ x,
                                                 const float* __restrict__ g,
                                                 const float* __restrict__ bta,
                                                 unsigned short* __restrict__ xn) {
  const int row = blockIdx.x;
  const int tid = threadIdx.x;
  const float4* xr = (const float4*)(x + (size_t)row * D_);
  float4 v0 = xr[tid];
  float4 v1 = xr[tid + 256];
  float s = v0.x + v0.y + v0.z + v0.w + v1.x + v1.y + v1.z + v1.w;
  float sq = v0.x * v0.x + v0.y * v0.y + v0.z * v0.z + v0.w * v0.w +
             v1.x * v1.x + v1.y * v1.y + v1.z * v1.z + v1.w * v1.w;
#pragma unroll
  for (int off = 32; off > 0; off >>= 1) {
    s += __shfl_xor(s, off);
    sq += __shfl_xor(sq, off);
  }
  __shared__ float ls[4], lq[4];
  const int lane = tid & 63, wave = tid >> 6;
  if (lane == 0) { ls[wave] = s; lq[wave] = sq; }
  __syncthreads();
  s = ls[0] + ls[1] + ls[2] + ls[3];
  sq = lq[0] + lq[1] + lq[2] + lq[3];
  const float mu = s * (1.0f / D_);
  const float rstd = rsqrtf(sq * (1.0f / D_) - mu * mu + 1e-5f);
  const float4* gv4 = (const float4*)g;
  const float4* bv4 = (const float4*)bta;
  ushort4* o4 = (ushort4*)(xn + (size_t)row * D_);
#pragma unroll
  for (int i = 0; i < 2; ++i) {
    const int idx = tid + i * 256;
    float4 vv = i == 0 ? v0 : v1;
    float4 gv = gv4[idx];
    float4 bv = bv4[idx];
    ushort4 o = make_ushort4(f2bf((vv.x - mu) * rstd * gv.x + bv.x),
                             f2bf((vv.y - mu) * rstd * gv.y + bv.y),
                             f2bf((vv.z - mu) * rstd * gv.z + bv.z),
                             f2bf((vv.w - mu) * rstd * gv.w + bv.w));
    o4[idx] = o;
  }
}

// ---------------- transpose + cast f32(RxC) -> bf16(CxR), with scale ----------------
__global__ void tcast(const float* __restrict__ in, unsigned short* __restrict__ out,
                      int R, int C, float scale) {
  __shared__ float tile[32][33];
  const int bc = blockIdx.x * 32;
  const int br = blockIdx.y * 32;
  const int tx = threadIdx.x, ty = threadIdx.y;
#pragma unroll
  for (int i = ty; i < 32; i += 8)
    tile[i][tx] = in[(size_t)(br + i) * C + bc + tx];
  __syncthreads();
#pragma unroll
  for (int i = ty; i < 32; i += 8)
    out[(size_t)(bc + i) * R + br + tx] = f2bf(tile[tx][i] * scale);
}

// ---------------- straight cast f32 -> bf16 (n4 float4 chunks) ----------------
__global__ void cast_bf16(const float* __restrict__ in, unsigned short* __restrict__ out,
                          int n4) {
  int i = blockIdx.x * blockDim.x + threadIdx.x;
  if (i >= n4) return;
  float4 v = ((const float4*)in)[i];
  ((ushort4*)out)[i] = make_ushort4(f2bf(v.x), f2bf(v.y), f2bf(v.z), f2bf(v.w));
}

// ---------------- bf16->bf16 transpose of V half of kv: vt[b][d][j] ----------------
__global__ void vtrans(const unsigned short* __restrict__ kvb, unsigned short* __restrict__ vt) {
  __shared__ unsigned short tile[32][33];
  const int jt = blockIdx.x * 32;
  const int dt = blockIdx.y * 32;
  const int b = blockIdx.z;
  const int tx = threadIdx.x, ty = threadIdx.y;
#pragma unroll
  for (int i = ty; i < 32; i += 8)
    tile[i][tx] = kvb[(size_t)(b * J_ + jt + i) * (2 * INNER_) + INNER_ + dt + tx];
  __syncthreads();
#pragma unroll
  for (int i = ty; i < 32; i += 8)
    vt[(size_t)(b * INNER_ + dt + i) * J_ + jt + tx] = tile[tx][i];
}

// ============ 8-wave 2-phase pipelined MFMA GEMM (128x256, BK=64) ============
template <bool BF16OUT>
__global__ __launch_bounds__(512, 2) void gemm_8ph(const unsigned short* __restrict__ Ag,
                                                   const unsigned short* __restrict__ Bg,
                                                   void* __restrict__ Cv,
                                                   int M, int N, int K) {
  __shared__ __align__(16) unsigned short lds[2][24576];
  const int tid = threadIdx.x;
  const int lane = tid & 63;
  const int wave = tid >> 6;
  const int l15 = lane & 15;
  const int lg8 = (lane >> 4) << 3;  // 0,8,16,24 shorts
  const int wr64 = (wave >> 2) << 6; // 0 or 64
  const int wc16 = (wave & 3) << 4;  // 0,16,32,48

  const int nwg = gridDim.x;
  int wg = ((int)blockIdx.x & 7) * (nwg >> 3) + ((int)blockIdx.x >> 3);
  const int gridM = M >> 7;
  const long row0 = (long)(wg % gridM) << 7;
  const long col0 = (long)(wg / gridM) << 8;

  auto stageA = [&](int buf, int kt, int r) {
    const int i = r * 512 + tid;
    const int row = i >> 3;
    const int c = (i & 7) ^ (row & 7);
    stage16(Ag + (size_t)(row0 + row) * K + kt + c * 8, &lds[buf][i * 8]);
  };
  auto stageB = [&](int buf, int kt, int r) {  // r in 0..3; 0,1=Btop 2,3=Bbot
    const int i = r * 512 + tid;
    const int row = i >> 3;
    const int c = (i & 7) ^ (row & 7);
    stage16(Bg + (size_t)(col0 + row) * K + kt + c * 8, &lds[buf][8192 + i * 8]);
  };

  const int NT = K >> 6;
  stageA(0, 0, 0); stageA(0, 0, 1);
  stageB(0, 0, 0); stageB(0, 0, 1); stageB(0, 0, 2); stageB(0, 0, 3);
  stageA(1, 64, 0); stageA(1, 64, 1);
  stageB(1, 64, 0); stageB(1, 64, 1); stageB(1, 64, 2); stageB(1, 64, 3);
  asm volatile("s_waitcnt vmcnt(6)" ::: "memory");
  asm volatile("s_barrier" ::: "memory");

  f32x4 acc[4][4] = {};
  int cur = 0;
  for (int t = 0; t < NT; ++t, cur ^= 1) {
    const unsigned short* Ab = &lds[cur][0];
    const unsigned short* Bb = &lds[cur][8192];
    bf16x8 af[4][2], bfr[4][2];
#pragma unroll
    for (int m = 0; m < 4; ++m)
#pragma unroll
      for (int kk = 0; kk < 2; ++kk) {
        const int row = wr64 + m * 16 + l15;
        af[m][kk] = *(const bf16x8*)(Ab + row * 64 + ((kk * 32 + lg8) ^ ((row & 7) << 3)));
      }
#pragma unroll
    for (int n = 0; n < 2; ++n)
#pragma unroll
      for (int kk = 0; kk < 2; ++kk) {
        const int brow = n * 64 + wc16 + l15;
        bfr[n][kk] = *(const bf16x8*)(Bb + brow * 64 + ((kk * 32 + lg8) ^ ((brow & 7) << 3)));
      }
    if (t >= 1 && t + 1 < NT) {
      stageB(cur ^ 1, (t + 1) << 6, 2); stageB(cur ^ 1, (t + 1) << 6, 3);
    }
    asm volatile("s_waitcnt vmcnt(6)" ::: "memory");
    asm volatile("s_barrier" ::: "memory");
    asm volatile("s_waitcnt lgkmcnt(0)" ::: "memory");
    __builtin_amdgcn_s_setprio(1);
#pragma unroll
    for (int m = 0; m < 4; ++m)
#pragma unroll
      for (int n = 0; n < 2; ++n)
#pragma unroll
        for (int kk = 0; kk < 2; ++kk)
          acc[m][n] = __builtin_amdgcn_mfma_f32_16x16x32_bf16(af[m][kk], bfr[n][kk], acc[m][n], 0, 0, 0);
    __builtin_amdgcn_s_setprio(0);
    asm volatile("s_barrier" ::: "memory");
#pragma unroll
    for (int n = 2; n < 4; ++n)
#pragma unroll
      for (int kk = 0; kk < 2; ++kk) {
        const int brow = n * 64 + wc16 + l15;
        bfr[n][kk] = *(const bf16x8*)(Bb + brow * 64 + ((kk * 32 + lg8) ^ ((brow & 7) << 3)));
      }
    if (t + 2 < NT) {
      stageA(cur, (t + 2) << 6, 0); stageA(cur, (t + 2) << 6, 1);
      stageB(cur, (t + 2) << 6, 0); stageB(cur, (t + 2) << 6, 1);
    }
    asm volatile("s_waitcnt vmcnt(6)" ::: "memory");
    asm volatile("s_barrier" ::: "memory");
    asm volatile("s_waitcnt lgkmcnt(0)" ::: "memory");
    __builtin_amdgcn_s_setprio(1);
#pragma unroll
    for (int m = 0; m < 4; ++m)
#pragma unroll
      for (int n = 2; n < 4; ++n)
#pragma unroll
        for (int kk = 0; kk < 2; ++kk)
          acc[m][n] = __builtin_amdgcn_mfma_f32_16x16x32_bf16(af[m][kk], bfr[n][kk], acc[m][n], 0, 0, 0);
    __builtin_amdgcn_s_setprio(0);
    asm volatile("s_barrier" ::: "memory");
  }

  const int cr = (lane >> 4) << 2;
#pragma unroll
  for (int m = 0; m < 4; ++m)
#pragma unroll
    for (int n = 0; n < 4; ++n)
#pragma unroll
      for (int j = 0; j < 4; ++j) {
        const size_t idx = (row0 + wr64 + m * 16 + cr + j) * (size_t)N + col0 + n * 64 + wc16 + l15;
        if constexpr (BF16OUT)
          ((unsigned short*)Cv)[idx] = f2bf(acc[m][n][j]);
        else
          ((float*)Cv)[idx] = acc[m][n][j];
      }
}

// ============ 256x256 deep-pipelined MFMA GEMM (m201-style 4-phase, BK=64) ============
// 8 waves = 2M x 4N, per-wave 128x64 (acc[8][4]). LDS 128KB: 2 bufs x (A 32KB | B 32KB).
// Phases per K-tile t (buf c=t&1), 16 MFMA each:
//  P1: ds A m0-3 (8) + B n0-1 (4); stage A-top(t+1)->buf c^1 ; MFMA m0-3 x n0-1
//  P2: ds B n2-3 (4);              stage A-bot(t+1)->buf c^1 ; MFMA m0-3 x n2-3
//  P3: ds A m4-7 (8, overwrite af);stage B-top(t+2)->buf c   ; MFMA m4-7 x n0-1
//  P4: (no ds);                    stage B-bot(t+2)->buf c   ; vmcnt(4); MFMA m4-7 x n2-3
// Safety: A-region(c^1) last read at (t-1).P3 (>=2 barriers); B-region(c) fully read by
// this tile's P2 (>=1 barrier). vmcnt(4) leaves exactly B(t+2)'s 4 loads in flight and
// guarantees A(t+1),B(t+1) landed before (t+1).P1's ds_reads.
template <bool BF16OUT>
__global__ __launch_bounds__(512, 2) void gemm256(const unsigned short* __restrict__ Ag,
                                                  const unsigned short* __restrict__ Bg,
                                                  void* __restrict__ Cv,
                                                  int M, int N, int K) {
  __shared__ __align__(16) unsigned short lds[2][32768];
  const int tid = threadIdx.x;
  const int lane = tid & 63;
  const int wave = tid >> 6;
  const int l15 = lane & 15;
  const int lg8 = (lane >> 4) << 3;
  const int wm = (wave >> 2) << 7;  // 0 or 128
  const int wn = (wave & 3) << 6;   // 0,64,128,192

  const int nwg = gridDim.x;
  int wg = ((int)blockIdx.x & 7) * (nwg >> 3) + ((int)blockIdx.x >> 3);
  const int gridM = M >> 8;
  const long row0 = (long)(wg % gridM) << 8;
  const long col0 = (long)(wg / gridM) << 8;

  auto stA = [&](int buf, int kt, int r) {  // r 0..3: rows r*64 .. r*64+63
    const int i = r * 512 + tid;
    const int row = i >> 3;
    const int c = (i & 7) ^ (row & 7);
    stage16(Ag + (size_t)(row0 + row) * K + kt + c * 8, &lds[buf][i * 8]);
  };
  auto stB = [&](int buf, int kt, int r) {
    const int i = r * 512 + tid;
    const int row = i >> 3;
    const int c = (i & 7) ^ (row & 7);
    stage16(Bg + (size_t)(col0 + row) * K + kt + c * 8, &lds[buf][16384 + i * 8]);
  };

  const int NT = K >> 6;
  // prologue FIFO: B(0)x4, A(0)x4, B(1)x4 ; vmcnt(4) => tile0 fully landed
  stB(0, 0, 0); stB(0, 0, 1); stB(0, 0, 2); stB(0, 0, 3);
  stA(0, 0, 0); stA(0, 0, 1); stA(0, 0, 2); stA(0, 0, 3);
  stB(1, 64, 0); stB(1, 64, 1); stB(1, 64, 2); stB(1, 64, 3);
  asm volatile("s_waitcnt vmcnt(4)" ::: "memory");
  asm volatile("s_barrier" ::: "memory");

  f32x4 acc[8][4] = {};
  int cur = 0;
  for (int t = 0; t < NT; ++t, cur ^= 1) {
    const unsigned short* Ab = &lds[cur][0];
    const unsigned short* Bb = &lds[cur][16384];
    bf16x8 af[4][2], bfr[4][2];
    const int ktn = (t + 1) << 6;
    const int ktn2 = (t + 2) << 6;
    // ---------- P1: m0-3 x n0-1 ----------
#pragma unroll
    for (int m = 0; m < 4; ++m)
#pragma unroll
      for (int kk = 0; kk < 2; ++kk) {
        const int row = wm + m * 16 + l15;
        af[m][kk] = *(const bf16x8*)(Ab + row * 64 + ((kk * 32 + lg8) ^ ((row & 7) << 3)));
      }
#pragma unroll
    for (int n = 0; n < 2; ++n)
#pragma unroll
      for (int kk = 0; kk < 2; ++kk) {
        const int brow = wn + n * 16 + l15;
        bfr[n][kk] = *(const bf16x8*)(Bb + brow * 64 + ((kk * 32 + lg8) ^ ((brow & 7) << 3)));
      }
    if (t + 1 < NT) { stA(cur ^ 1, ktn, 0); stA(cur ^ 1, ktn, 1); }
    asm volatile("s_barrier" ::: "memory");
    asm volatile("s_waitcnt lgkmcnt(0)" ::: "memory");
    __builtin_amdgcn_s_setprio(1);
#pragma unroll
    for (int m = 0; m < 4; ++m)
#pragma unroll
      for (int n = 0; n < 2; ++n)
#pragma unroll
        for (int kk = 0; kk < 2; ++kk)
          acc[m][n] = __builtin_amdgcn_mfma_f32_16x16x32_bf16(af[m][kk], bfr[n][kk], acc[m][n], 0, 0, 0);
    __builtin_amdgcn_s_setprio(0);
    asm volatile("s_barrier" ::: "memory");
    // ---------- P2: m0-3 x n2-3 ----------
#pragma unroll
    for (int n = 2; n < 4; ++n)
#pragma unroll
      for (int kk = 0; kk < 2; ++kk) {
        const int brow = wn + n * 16 + l15;
        bfr[n][kk] = *(const bf16x8*)(Bb + brow * 64 + ((kk * 32 + lg8) ^ ((brow & 7) << 3)));
      }
    if (t + 1 < NT) { stA(cur ^ 1, ktn, 2); stA(cur ^ 1, ktn, 3); }
    asm volatile("s_barrier" ::: "memory");
    asm volatile("s_waitcnt lgkmcnt(0)" ::: "memory");
    __builtin_amdgcn_s_setprio(1);
#pragma unroll
    for (int m = 0; m < 4; ++m)
#pragma unroll
      for (int n = 2; n < 4; ++n)
#pragma unroll
        for (int kk = 0; kk < 2; ++kk)
          acc[m][n] = __builtin_amdgcn_mfma_f32_16x16x32_bf16(af[m][kk], bfr[n][kk], acc[m][n], 0, 0, 0);
    __builtin_amdgcn_s_setprio(0);
    asm volatile("s_barrier" ::: "memory");
    // ---------- P3: m4-7 x n0-1 (overwrite af) ----------
#pragma unroll
    for (int m = 0; m < 4; ++m)
#pragma unroll
      for (int kk = 0; kk < 2; ++kk) {
        const int row = wm + (m + 4) * 16 + l15;
        af[m][kk] = *(const bf16x8*)(Ab + row * 64 + ((kk * 32 + lg8) ^ ((row & 7) << 3)));
      }
    if (t + 2 < NT) { stB(cur, ktn2, 0); stB(cur, ktn2, 1); }
    asm volatile("s_barrier" ::: "memory");
    asm volatile("s_waitcnt lgkmcnt(0)" ::: "memory");
    __builtin_amdgcn_s_setprio(1);
#pragma unroll
    for (int m = 0; m < 4; ++m)
#pragma unroll
      for (int n = 0; n < 2; ++n)
#pragma unroll
        for (int kk = 0; kk < 2; ++kk)
          acc[m + 4][n] = __builtin_amdgcn_mfma_f32_16x16x32_bf16(af[m][kk], bfr[n][kk], acc[m + 4][n], 0, 0, 0);
    __builtin_amdgcn_s_setprio(0);
    asm volatile("s_barrier" ::: "memory");
    // ---------- P4: m4-7 x n2-3 ----------
    if (t + 2 < NT) { stB(cur, ktn2, 2); stB(cur, ktn2, 3); }
    asm volatile("s_waitcnt vmcnt(4)" ::: "memory");
    asm volatile("s_barrier" ::: "memory");
    __builtin_amdgcn_s_setprio(1);
#pragma unroll
    for (int m = 0; m < 4; ++m)
#pragma unroll
      for (int n = 2; n < 4; ++n)
#pragma unroll
        for (int kk = 0; kk < 2; ++kk)
          acc[m + 4][n] = __builtin_amdgcn_mfma_f32_16x16x32_bf16(af[m][kk], bfr[n][kk], acc[m + 4][n], 0, 0, 0);
    __builtin_amdgcn_s_setprio(0);
    asm volatile("s_barrier" ::: "memory");
  }

  const int cr = (lane >> 4) << 2;
#pragma unroll
  for (int m = 0; m < 8; ++m)
#pragma unroll
    for (int n = 0; n < 4; ++n)
#pragma unroll
      for (int j = 0; j < 4; ++j) {
        const size_t idx = (row0 + wm + m * 16 + cr + j) * (size_t)N + col0 + wn + n * 16 + l15;
        if constexpr (BF16OUT)
          ((unsigned short*)Cv)[idx] = f2bf(acc[m][n][j]);
        else
          ((float*)Cv)[idx] = acc[m][n][j];
      }
}

// ---------------- MFMA masked cross-attention ----------------
__global__ __launch_bounds__(256) void attn2_kernel(
    const unsigned short* __restrict__ qb,
    const unsigned short* __restrict__ kvb,
    const unsigned short* __restrict__ vt,
    const int* __restrict__ img_idx,
    unsigned short* __restrict__ attn_out) {
  __shared__ unsigned short Pl[4][64 * 72];
  const int tid = threadIdx.x;
  const int lane = tid & 63;
  const int w = tid >> 6;
  int bid = blockIdx.x;
  const int hg = bid & 3; bid >>= 2;
  const int tile = bid & 31; bid >>= 5;
  const int b = bid;
  const int t0 = tile * 64;
  const int h = hg * 4 + w;
  const int l15 = lane & 15;
  const int lg = lane >> 4;

  const int* ii = img_idx + b * T_ + t0;
  int myimg = ii[lane];
  int tmin = myimg, tmax = myimg;
#pragma unroll
  for (int off = 1; off < 64; off <<= 1) {
    tmin = min(tmin, __shfl_xor(tmin, off));
    tmax = max(tmax, __shfl_xor(tmax, off));
  }
  unsigned short* op = attn_out + (size_t)(b * T_ + t0) * INNER_ + h * DH_;
  if (tmin < 0) {
    for (int r = 0; r < 64; ++r)
      if (ii[r] < 0) op[(size_t)r * INNER_ + lane] = 0;
  }
  if (tmax < 0) return;

  bf16x8 qa[4][2];
  const unsigned short* qrow = qb + (size_t)(b * T_ + t0) * INNER_ + h * DH_;
#pragma unroll
  for (int m = 0; m < 4; ++m)
#pragma unroll
    for (int kk = 0; kk < 2; ++kk)
      qa[m][kk] = *(const bf16x8*)(qrow + (size_t)(l15 + m * 16) * INNER_ + kk * 32 + lg * 8);

  unsigned short* pw = Pl[w];
  for (int img = max(tmin, 0); img <= tmax; ++img) {
    const unsigned short* Kb = kvb + (size_t)(b * J_ + img * NLAT_) * (2 * INNER_) + h * DH_;
    f32x4 acc[4][4] = {};
#pragma unroll
    for (int kk = 0; kk < 2; ++kk) {
      bf16x8 bfr[4];
#pragma unroll
      for (int n = 0; n < 4; ++n)
        bfr[n] = *(const bf16x8*)(Kb + (size_t)(l15 + n * 16) * (2 * INNER_) + kk * 32 + lg * 8);
#pragma unroll
      for (int m = 0; m < 4; ++m)
#pragma unroll
        for (int n = 0; n < 4; ++n)
          acc[m][n] = __builtin_amdgcn_mfma_f32_16x16x32_bf16(qa[m][kk], bfr[n], acc[m][n], 0, 0, 0);
    }
#pragma unroll
    for (int m = 0; m < 4; ++m) {
#pragma unroll
      for (int j = 0; j < 4; ++j) {
        float mx = fmaxf(fmaxf(acc[m][0][j], acc[m][1][j]), fmaxf(acc[m][2][j], acc[m][3][j]));
#pragma unroll
        for (int off = 1; off < 16; off <<= 1) mx = fmaxf(mx, __shfl_xor(mx, off));
        float sum = 0.f;
#pragma unroll
        for (int n = 0; n < 4; ++n) {
          float e = __expf(acc[m][n][j] - mx);
          acc[m][n][j] = e;
          sum += e;
        }
#pragma unroll
        for (int off = 1; off < 16; off <<= 1) sum += __shfl_xor(sum, off);
        const float ri = 1.0f / sum;
        const int row = m * 16 + lg * 4 + j;
#pragma unroll
        for (int n = 0; n < 4; ++n)
          pw[row * 72 + n * 16 + l15] = f2bf(acc[m][n][j] * ri);
      }
    }
    const unsigned short* Vb = vt + (size_t)(b * INNER_ + h * DH_) * J_ + img * NLAT_;
    f32x4 oacc[4][4] = {};
#pragma unroll
    for (int kk = 0; kk < 2; ++kk) {
      bf16x8 pa[4], bfr[4];
#pragma unroll
      for (int m = 0; m < 4; ++m) {
        bf16x4 lo = *(const bf16x4*)(pw + (m * 16 + l15) * 72 + kk * 32 + lg * 8);
        bf16x4 hi = *(const bf16x4*)(pw + (m * 16 + l15) * 72 + kk * 32 + lg * 8 + 4);
        bf16x8 v;
#pragma unroll
        for (int e = 0; e < 4; ++e) { v[e] = lo[e]; v[e + 4] = hi[e]; }
        pa[m] = v;
      }
#pragma unroll
      for (int n = 0; n < 4; ++n)
        bfr[n] = *(const bf16x8*)(Vb + (size_t)(l15 + n * 16) * J_ + kk * 32 + lg * 8);
#pragma unroll
      for (int m = 0; m < 4; ++m)
#pragma unroll
        for (int n = 0; n < 4; ++n)
          oacc[m][n] = __builtin_amdgcn_mfma_f32_16x16x32_bf16(pa[m], bfr[n], oacc[m][n], 0, 0, 0);
    }
#pragma unroll
    for (int m = 0; m < 4; ++m)
#pragma unroll
      for (int j = 0; j < 4; ++j) {
        const int row = m * 16 + lg * 4 + j;
        if (ii[row] == img) {
#pragma unroll
          for (int n = 0; n < 4; ++n)
            op[(size_t)row * INNER_ + n * 16 + l15] = f2bf(oacc[m][n][j]);
        }
      }
  }
}

extern "C" void kernel_launch(void* const* d_in, const int* in_sizes, int n_in,
                              void* d_out, int out_size, void* d_ws, size_t ws_size,
                              hipStream_t stream) {
  const float* x = (const float*)d_in[0];
  const float* media = (const float*)d_in[1];
  const void* mloc = d_in[2];
  const float* gamma = (const float*)d_in[3];
  const float* beta = (const float*)d_in[4];
  const float* Wq = (const float*)d_in[5];
  const float* Wkv = (const float*)d_in[6];
  const float* Wout = (const float*)d_in[7];
  float* out = (float*)d_out;

  char* ws = (char*)d_ws;
  unsigned short* xn = (unsigned short*)(ws);
  unsigned short* wqt = (unsigned short*)(ws + 33554432);
  unsigned short* wkvt = (unsigned short*)(ws + 37748736);
  unsigned short* woutt = (unsigned short*)(ws + 41943040);
  unsigned short* medb = (unsigned short*)(ws + 46137344);
  unsigned short* qb = (unsigned short*)(ws + 50331648);
  unsigned short* kvb = (unsigned short*)(ws + 67108864);
  unsigned short* vt = (unsigned short*)(ws + 75497472);
  int* img_idx = (int*)(ws + 79691776);
  unsigned short* attn_out = xn;

  scan_kernel<<<B_, 256, 0, stream>>>(mloc, img_idx);
  ln_kernel<<<B_ * T_, 256, 0, stream>>>(x, gamma, beta, xn);
  tcast<<<dim3(INNER_ / 32, D_ / 32), dim3(32, 8), 0, stream>>>(Wq, wqt, D_, INNER_, 0.125f);
  tcast<<<dim3(2 * INNER_ / 32, DV_ / 32), dim3(32, 8), 0, stream>>>(Wkv, wkvt, DV_, 2 * INNER_, 1.0f);
  tcast<<<dim3(D_ / 32, INNER_ / 32), dim3(32, 8), 0, stream>>>(Wout, woutt, INNER_, D_, 1.0f);
  cast_bf16<<<(B_ * J_ * DV_ / 4 + 255) / 256, 256, 0, stream>>>(media, medb, B_ * J_ * DV_ / 4);
  // GEMM1: q = xn @ Wq' (M=8192,N=1024,K=2048) -> 256 blocks (128x256 kernel)
  gemm_8ph<true><<<(B_ * T_ / 128) * (INNER_ / 256), 512, 0, stream>>>(xn, wqt, qb, B_ * T_, INNER_, D_);
  // GEMM2: kv = media @ Wkv (M=2048,N=2048,K=1024) -> 128 blocks
  gemm_8ph<true><<<(B_ * J_ / 128) * (2 * INNER_ / 256), 512, 0, stream>>>(medb, wkvt, kvb, B_ * J_, 2 * INNER_, DV_);
  vtrans<<<dim3(J_ / 32, INNER_ / 32, B_), dim3(32, 8), 0, stream>>>(kvb, vt);
  attn2_kernel<<<B_ * (T_ / 64) * 4, 256, 0, stream>>>(qb, kvb, vt, img_idx, attn_out);
  // GEMM3: out = attn_out @ Wout (M=8192,N=2048,K=1024) -> 256 blocks (256x256 deep kernel)
  gemm256<false><<<(B_ * T_ / 256) * (D_ / 256), 512, 0, stream>>>(attn_out, woutt, out, B_ * T_, D_, INNER_);
}

// Round 5
// 153.606 us; speedup vs baseline: 2.9514x; 1.0716x over previous
//
#include <hip/hip_runtime.h>
#include <hip/hip_bf16.h>

#define B_ 4
#define T_ 2048
#define D_ 2048
#define DV_ 1024
#define TIMG_ 8
#define NLAT_ 64
#define H_ 16
#define DH_ 64
#define INNER_ 1024
#define J_ (TIMG_ * NLAT_)  // 512

using f32x4 = __attribute__((ext_vector_type(4))) float;
using bf16x8 = __attribute__((ext_vector_type(8))) short;
using bf16x4 = __attribute__((ext_vector_type(4))) short;

__device__ __forceinline__ unsigned short f2bf(float f) {
  union { float f; unsigned int u; } c{f};
  unsigned int r = c.u + 0x7FFFu + ((c.u >> 16) & 1u);  // RNE
  return (unsigned short)(r >> 16);
}

__device__ __forceinline__ void stage16(const unsigned short* g, unsigned short* l) {
  __builtin_amdgcn_global_load_lds(
      (const __attribute__((address_space(1))) unsigned int*)g,
      (__attribute__((address_space(3))) unsigned int*)l, 16, 0, 0);
}

// ================= fused prep: ln | scan | tcast x3 | cast =================
// block ranges: [0,8192) ln rows; [8192,8196) scan; then 4 x 2048 tcast/cast.
__global__ __launch_bounds__(256) void prep_kernel(
    const float* __restrict__ x, const void* __restrict__ locs,
    const float* __restrict__ g, const float* __restrict__ bta,
    const float* __restrict__ Wq, const float* __restrict__ Wkv,
    const float* __restrict__ Wout, const float* __restrict__ media,
    unsigned short* __restrict__ xn, int* __restrict__ img_idx,
    unsigned short* __restrict__ wqt, unsigned short* __restrict__ wkvt,
    unsigned short* __restrict__ woutt, unsigned short* __restrict__ medb) {
  __shared__ __align__(16) float smf[1056];  // tcast tile 32x33; scan/ln reuse
  const int tid = threadIdx.x;
  int blk = blockIdx.x;

  if (blk < 8192) {
    // ---------------- LayerNorm ----------------
    const int row = blk;
    const float4* xr = (const float4*)(x + (size_t)row * D_);
    float4 v0 = xr[tid];
    float4 v1 = xr[tid + 256];
    float s = v0.x + v0.y + v0.z + v0.w + v1.x + v1.y + v1.z + v1.w;
    float sq = v0.x * v0.x + v0.y * v0.y + v0.z * v0.z + v0.w * v0.w +
               v1.x * v1.x + v1.y * v1.y + v1.z * v1.z + v1.w * v1.w;
#pragma unroll
    for (int off = 32; off > 0; off >>= 1) {
      s += __shfl_xor(s, off);
      sq += __shfl_xor(sq, off);
    }
    const int lane = tid & 63, wave = tid >> 6;
    if (lane == 0) { smf[wave] = s; smf[4 + wave] = sq; }
    __syncthreads();
    s = smf[0] + smf[1] + smf[2] + smf[3];
    sq = smf[4] + smf[5] + smf[6] + smf[7];
    const float mu = s * (1.0f / D_);
    const float rstd = rsqrtf(sq * (1.0f / D_) - mu * mu + 1e-5f);
    const float4* gv4 = (const float4*)g;
    const float4* bv4 = (const float4*)bta;
    ushort4* o4 = (ushort4*)(xn + (size_t)row * D_);
#pragma unroll
    for (int i = 0; i < 2; ++i) {
      const int idx = tid + i * 256;
      float4 vv = i == 0 ? v0 : v1;
      float4 gv = gv4[idx];
      float4 bv = bv4[idx];
      o4[idx] = make_ushort4(f2bf((vv.x - mu) * rstd * gv.x + bv.x),
                             f2bf((vv.y - mu) * rstd * gv.y + bv.y),
                             f2bf((vv.z - mu) * rstd * gv.z + bv.z),
                             f2bf((vv.w - mu) * rstd * gv.w + bv.w));
    }
    return;
  }
  blk -= 8192;
  if (blk < 4) {
    // ---------------- media_locations scan ----------------
    int* sm = (int*)smf;
    const int b = blk;
    const unsigned char* u8 = (const unsigned char*)locs;
    int cnt = 0;
    for (int i = tid; i < B_ * T_; i += 256) cnt += (u8[i] != 0) ? 1 : 0;
    sm[tid] = cnt;
    __syncthreads();
    for (int off = 128; off > 0; off >>= 1) {
      if (tid < off) sm[tid] += sm[tid + off];
      __syncthreads();
    }
    const bool u8mode = (sm[0] == B_ * TIMG_);
    __syncthreads();
    const int base = b * T_ + tid * 8;
    const int* i32 = (const int*)locs;
    int v[8];
    int ts = 0;
#pragma unroll
    for (int j = 0; j < 8; ++j) {
      v[j] = u8mode ? (u8[base + j] != 0 ? 1 : 0) : (i32[base + j] != 0 ? 1 : 0);
      ts += v[j];
    }
    sm[tid] = ts;
    __syncthreads();
    for (int off = 1; off < 256; off <<= 1) {
      int add = (tid >= off) ? sm[tid - off] : 0;
      __syncthreads();
      sm[tid] += add;
      __syncthreads();
    }
    int acc = sm[tid] - ts;
#pragma unroll
    for (int j = 0; j < 8; ++j) {
      acc += v[j];
      img_idx[base + j] = acc - 1;
    }
    return;
  }
  blk -= 4;
  // ---------------- tcast / cast ----------------
  const int tx = tid & 31, ty = tid >> 5;
  float (*tile)[33] = (float(*)[33])smf;
  const float* tin = nullptr;
  unsigned short* tout = nullptr;
  int R = 0, C = 0, bx = 0, by = 0;
  float scale = 1.0f;
  if (blk < 2048) {           // Wq: R=2048, C=1024, grid (32, 64)
    tin = Wq; tout = wqt; R = D_; C = INNER_; bx = blk & 31; by = blk >> 5; scale = 0.125f;
  } else if (blk < 4096) {    // Wkv: R=1024, C=2048, grid (64, 32)
    blk -= 2048;
    tin = Wkv; tout = wkvt; R = DV_; C = 2 * INNER_; bx = blk & 63; by = blk >> 6;
  } else if (blk < 6144) {    // Wout: R=1024, C=2048, grid (64, 32)
    blk -= 4096;
    tin = Wout; tout = woutt; R = INNER_; C = D_; bx = blk & 63; by = blk >> 6;
  } else {                    // cast media
    blk -= 6144;
    const int i = blk * 256 + tid;
    float4 v = ((const float4*)media)[i];
    ((ushort4*)medb)[i] = make_ushort4(f2bf(v.x), f2bf(v.y), f2bf(v.z), f2bf(v.w));
    return;
  }
  const int bc = bx * 32, br = by * 32;
#pragma unroll
  for (int i = ty; i < 32; i += 8)
    tile[i][tx] = tin[(size_t)(br + i) * C + bc + tx];
  __syncthreads();
#pragma unroll
  for (int i = ty; i < 32; i += 8)
    tout[(size_t)(bc + i) * R + br + tx] = f2bf(tile[tx][i] * scale);
}

// ---------------- bf16->bf16 transpose of V half of kv: vt[b][d][j] ----------------
__global__ void vtrans(const unsigned short* __restrict__ kvb, unsigned short* __restrict__ vt) {
  __shared__ unsigned short tile[32][33];
  const int jt = blockIdx.x * 32;
  const int dt = blockIdx.y * 32;
  const int b = blockIdx.z;
  const int tx = threadIdx.x, ty = threadIdx.y;
#pragma unroll
  for (int i = ty; i < 32; i += 8)
    tile[i][tx] = kvb[(size_t)(b * J_ + jt + i) * (2 * INNER_) + INNER_ + dt + tx];
  __syncthreads();
#pragma unroll
  for (int i = ty; i < 32; i += 8)
    vt[(size_t)(b * INNER_ + dt + i) * J_ + jt + tx] = tile[tx][i];
}

// ============ v2 128x256 2-phase GEMM: A dbuf + B tri-buf, 1 vmcnt/K-tile ============
// 8 waves 2Mx4N, per-wave 64x64, acc[4][4]. LDS 128KB: A 2x16KB @0, B 3x32KB @16384 shorts.
// Per K-tile t: P1 {ds A all(8)+B n0-1(4); stage A(t+1)x2 -> Abuf[(t+1)&1],
//   B(t+2)ab -> Bbuf[(t+2)%3]; bar; lgkm0; 16 MFMA; bar}
//   P2 {ds B n2-3(4); stage B(t+2)cd; vmcnt(4) [drains B(t+1)x4+A(t+1)x2, leaves
//   B(t+2)x4 in flight]; bar; lgkm0; 16 MFMA; bar}
// Region safety: A dest last read P1(t-1) (4 barriers); B dest holds t-1, last read
// P2(t-1) (>=1 barrier before P1(t) stage-issue). Tail: vmcnt(0) when t+2>=NT.
template <bool BF16OUT>
__global__ __launch_bounds__(512, 2) void gemm_bt2(const unsigned short* __restrict__ Ag,
                                                   const unsigned short* __restrict__ Bg,
                                                   void* __restrict__ Cv,
                                                   int M, int N, int K) {
  __shared__ __align__(16) unsigned short lds[65536];  // 128 KB
  const int tid = threadIdx.x;
  const int lane = tid & 63;
  const int wave = tid >> 6;
  const int l15 = lane & 15;
  const int lg8 = (lane >> 4) << 3;
  const int wr64 = (wave >> 2) << 6;
  const int wc16 = (wave & 3) << 4;

  const int nwg = gridDim.x;
  int wg = ((int)blockIdx.x & 7) * (nwg >> 3) + ((int)blockIdx.x >> 3);
  const int gridM = M >> 7;
  const long row0 = (long)(wg % gridM) << 7;
  const long col0 = (long)(wg / gridM) << 8;

  auto stA = [&](int t, int r) {  // r 0..1, rows r*64..r*64+63
    const int i = r * 512 + tid;
    const int row = i >> 3;
    const int c = (i & 7) ^ (row & 7);
    stage16(Ag + (size_t)(row0 + row) * K + (t << 6) + c * 8,
            &lds[(t & 1) * 8192 + i * 8]);
  };
  auto stB = [&](int t, int r) {  // r 0..3, rows r*64..r*64+63
    const int i = r * 512 + tid;
    const int row = i >> 3;
    const int c = (i & 7) ^ (row & 7);
    stage16(Bg + (size_t)(col0 + row) * K + (t << 6) + c * 8,
            &lds[16384 + (t % 3) * 16384 + i * 8]);
  };

  const int NT = K >> 6;
  // prologue: B0 x4, A0 x2, B1 x4 -> vmcnt(4) drains B0,A0; leaves B1 x4.
  stB(0, 0); stB(0, 1); stB(0, 2); stB(0, 3);
  stA(0, 0); stA(0, 1);
  stB(1, 0); stB(1, 1); stB(1, 2); stB(1, 3);
  asm volatile("s_waitcnt vmcnt(4)" ::: "memory");
  asm volatile("s_barrier" ::: "memory");

  f32x4 acc[4][4] = {};
  for (int t = 0; t < NT; ++t) {
    const unsigned short* Ab = &lds[(t & 1) * 8192];
    const unsigned short* Bb = &lds[16384 + (t % 3) * 16384];
    bf16x8 af[4][2], bfr[4][2];
    // ---------- P1 ----------
#pragma unroll
    for (int m = 0; m < 4; ++m)
#pragma unroll
      for (int kk = 0; kk < 2; ++kk) {
        const int row = wr64 + m * 16 + l15;
        af[m][kk] = *(const bf16x8*)(Ab + row * 64 + ((kk * 32 + lg8) ^ ((row & 7) << 3)));
      }
#pragma unroll
    for (int n = 0; n < 2; ++n)
#pragma unroll
      for (int kk = 0; kk < 2; ++kk) {
        const int brow = n * 64 + wc16 + l15;
        bfr[n][kk] = *(const bf16x8*)(Bb + brow * 64 + ((kk * 32 + lg8) ^ ((brow & 7) << 3)));
      }
    if (t + 1 < NT) { stA(t + 1, 0); stA(t + 1, 1); }
    if (t + 2 < NT) { stB(t + 2, 0); stB(t + 2, 1); }
    asm volatile("s_barrier" ::: "memory");
    asm volatile("s_waitcnt lgkmcnt(0)" ::: "memory");
    __builtin_amdgcn_s_setprio(1);
#pragma unroll
    for (int m = 0; m < 4; ++m)
#pragma unroll
      for (int n = 0; n < 2; ++n)
#pragma unroll
        for (int kk = 0; kk < 2; ++kk)
          acc[m][n] = __builtin_amdgcn_mfma_f32_16x16x32_bf16(af[m][kk], bfr[n][kk], acc[m][n], 0, 0, 0);
    __builtin_amdgcn_s_setprio(0);
    asm volatile("s_barrier" ::: "memory");
    // ---------- P2 ----------
#pragma unroll
    for (int n = 2; n < 4; ++n)
#pragma unroll
      for (int kk = 0; kk < 2; ++kk) {
        const int brow = n * 64 + wc16 + l15;
        bfr[n][kk] = *(const bf16x8*)(Bb + brow * 64 + ((kk * 32 + lg8) ^ ((brow & 7) << 3)));
      }
    if (t + 2 < NT) {
      stB(t + 2, 2); stB(t + 2, 3);
      asm volatile("s_waitcnt vmcnt(4)" ::: "memory");
    } else {
      asm volatile("s_waitcnt vmcnt(0)" ::: "memory");
    }
    asm volatile("s_barrier" ::: "memory");
    asm volatile("s_waitcnt lgkmcnt(0)" ::: "memory");
    __builtin_amdgcn_s_setprio(1);
#pragma unroll
    for (int m = 0; m < 4; ++m)
#pragma unroll
      for (int n = 2; n < 4; ++n)
#pragma unroll
        for (int kk = 0; kk < 2; ++kk)
          acc[m][n] = __builtin_amdgcn_mfma_f32_16x16x32_bf16(af[m][kk], bfr[n][kk], acc[m][n], 0, 0, 0);
    __builtin_amdgcn_s_setprio(0);
    asm volatile("s_barrier" ::: "memory");
  }

  const int cr = (lane >> 4) << 2;
#pragma unroll
  for (int m = 0; m < 4; ++m)
#pragma unroll
    for (int n = 0; n < 4; ++n)
#pragma unroll
      for (int j = 0; j < 4; ++j) {
        const size_t idx = (row0 + wr64 + m * 16 + cr + j) * (size_t)N + col0 + n * 64 + wc16 + l15;
        if constexpr (BF16OUT)
          ((unsigned short*)Cv)[idx] = f2bf(acc[m][n][j]);
        else
          ((float*)Cv)[idx] = acc[m][n][j];
      }
}

// ============ 256x256 deep-pipelined MFMA GEMM (4-phase, BK=64) ============
template <bool BF16OUT>
__global__ __launch_bounds__(512, 2) void gemm256(const unsigned short* __restrict__ Ag,
                                                  const unsigned short* __restrict__ Bg,
                                                  void* __restrict__ Cv,
                                                  int M, int N, int K) {
  __shared__ __align__(16) unsigned short lds[2][32768];
  const int tid = threadIdx.x;
  const int lane = tid & 63;
  const int wave = tid >> 6;
  const int l15 = lane & 15;
  const int lg8 = (lane >> 4) << 3;
  const int wm = (wave >> 2) << 7;
  const int wn = (wave & 3) << 6;

  const int nwg = gridDim.x;
  int wg = ((int)blockIdx.x & 7) * (nwg >> 3) + ((int)blockIdx.x >> 3);
  const int gridM = M >> 8;
  const long row0 = (long)(wg % gridM) << 8;
  const long col0 = (long)(wg / gridM) << 8;

  auto stA = [&](int buf, int kt, int r) {
    const int i = r * 512 + tid;
    const int row = i >> 3;
    const int c = (i & 7) ^ (row & 7);
    stage16(Ag + (size_t)(row0 + row) * K + kt + c * 8, &lds[buf][i * 8]);
  };
  auto stB = [&](int buf, int kt, int r) {
    const int i = r * 512 + tid;
    const int row = i >> 3;
    const int c = (i & 7) ^ (row & 7);
    stage16(Bg + (size_t)(col0 + row) * K + kt + c * 8, &lds[buf][16384 + i * 8]);
  };

  const int NT = K >> 6;
  stB(0, 0, 0); stB(0, 0, 1); stB(0, 0, 2); stB(0, 0, 3);
  stA(0, 0, 0); stA(0, 0, 1); stA(0, 0, 2); stA(0, 0, 3);
  stB(1, 64, 0); stB(1, 64, 1); stB(1, 64, 2); stB(1, 64, 3);
  asm volatile("s_waitcnt vmcnt(4)" ::: "memory");
  asm volatile("s_barrier" ::: "memory");

  f32x4 acc[8][4] = {};
  int cur = 0;
  for (int t = 0; t < NT; ++t, cur ^= 1) {
    const unsigned short* Ab = &lds[cur][0];
    const unsigned short* Bb = &lds[cur][16384];
    bf16x8 af[4][2], bfr[4][2];
    const int ktn = (t + 1) << 6;
    const int ktn2 = (t + 2) << 6;
    // ---------- P1: m0-3 x n0-1 ----------
#pragma unroll
    for (int m = 0; m < 4; ++m)
#pragma unroll
      for (int kk = 0; kk < 2; ++kk) {
        const int row = wm + m * 16 + l15;
        af[m][kk] = *(const bf16x8*)(Ab + row * 64 + ((kk * 32 + lg8) ^ ((row & 7) << 3)));
      }
#pragma unroll
    for (int n = 0; n < 2; ++n)
#pragma unroll
      for (int kk = 0; kk < 2; ++kk) {
        const int brow = wn + n * 16 + l15;
        bfr[n][kk] = *(const bf16x8*)(Bb + brow * 64 + ((kk * 32 + lg8) ^ ((brow & 7) << 3)));
      }
    if (t + 1 < NT) { stA(cur ^ 1, ktn, 0); stA(cur ^ 1, ktn, 1); }
    asm volatile("s_barrier" ::: "memory");
    asm volatile("s_waitcnt lgkmcnt(0)" ::: "memory");
    __builtin_amdgcn_s_setprio(1);
#pragma unroll
    for (int m = 0; m < 4; ++m)
#pragma unroll
      for (int n = 0; n < 2; ++n)
#pragma unroll
        for (int kk = 0; kk < 2; ++kk)
          acc[m][n] = __builtin_amdgcn_mfma_f32_16x16x32_bf16(af[m][kk], bfr[n][kk], acc[m][n], 0, 0, 0);
    __builtin_amdgcn_s_setprio(0);
    asm volatile("s_barrier" ::: "memory");
    // ---------- P2: m0-3 x n2-3 ----------
#pragma unroll
    for (int n = 2; n < 4; ++n)
#pragma unroll
      for (int kk = 0; kk < 2; ++kk) {
        const int brow = wn + n * 16 + l15;
        bfr[n][kk] = *(const bf16x8*)(Bb + brow * 64 + ((kk * 32 + lg8) ^ ((brow & 7) << 3)));
      }
    if (t + 1 < NT) { stA(cur ^ 1, ktn, 2); stA(cur ^ 1, ktn, 3); }
    asm volatile("s_barrier" ::: "memory");
    asm volatile("s_waitcnt lgkmcnt(0)" ::: "memory");
    __builtin_amdgcn_s_setprio(1);
#pragma unroll
    for (int m = 0; m < 4; ++m)
#pragma unroll
      for (int n = 2; n < 4; ++n)
#pragma unroll
        for (int kk = 0; kk < 2; ++kk)
          acc[m][n] = __builtin_amdgcn_mfma_f32_16x16x32_bf16(af[m][kk], bfr[n][kk], acc[m][n], 0, 0, 0);
    __builtin_amdgcn_s_setprio(0);
    asm volatile("s_barrier" ::: "memory");
    // ---------- P3: m4-7 x n0-1 ----------
#pragma unroll
    for (int m = 0; m < 4; ++m)
#pragma unroll
      for (int kk = 0; kk < 2; ++kk) {
        const int row = wm + (m + 4) * 16 + l15;
        af[m][kk] = *(const bf16x8*)(Ab + row * 64 + ((kk * 32 + lg8) ^ ((row & 7) << 3)));
      }
    if (t + 2 < NT) { stB(cur, ktn2, 0); stB(cur, ktn2, 1); }
    asm volatile("s_barrier" ::: "memory");
    asm volatile("s_waitcnt lgkmcnt(0)" ::: "memory");
    __builtin_amdgcn_s_setprio(1);
#pragma unroll
    for (int m = 0; m < 4; ++m)
#pragma unroll
      for (int n = 0; n < 2; ++n)
#pragma unroll
        for (int kk = 0; kk < 2; ++kk)
          acc[m + 4][n] = __builtin_amdgcn_mfma_f32_16x16x32_bf16(af[m][kk], bfr[n][kk], acc[m + 4][n], 0, 0, 0);
    __builtin_amdgcn_s_setprio(0);
    asm volatile("s_barrier" ::: "memory");
    // ---------- P4: m4-7 x n2-3 ----------
    if (t + 2 < NT) { stB(cur, ktn2, 2); stB(cur, ktn2, 3); }
    asm volatile("s_waitcnt vmcnt(4)" ::: "memory");
    asm volatile("s_barrier" ::: "memory");
    __builtin_amdgcn_s_setprio(1);
#pragma unroll
    for (int m = 0; m < 4; ++m)
#pragma unroll
      for (int n = 2; n < 4; ++n)
#pragma unroll
        for (int kk = 0; kk < 2; ++kk)
          acc[m + 4][n] = __builtin_amdgcn_mfma_f32_16x16x32_bf16(af[m][kk], bfr[n][kk], acc[m + 4][n], 0, 0, 0);
    __builtin_amdgcn_s_setprio(0);
    asm volatile("s_barrier" ::: "memory");
  }

  const int cr = (lane >> 4) << 2;
#pragma unroll
  for (int m = 0; m < 8; ++m)
#pragma unroll
    for (int n = 0; n < 4; ++n)
#pragma unroll
      for (int j = 0; j < 4; ++j) {
        const size_t idx = (row0 + wm + m * 16 + cr + j) * (size_t)N + col0 + wn + n * 16 + l15;
        if constexpr (BF16OUT)
          ((unsigned short*)Cv)[idx] = f2bf(acc[m][n][j]);
        else
          ((float*)Cv)[idx] = acc[m][n][j];
      }
}

// ---------------- MFMA masked cross-attention ----------------
__global__ __launch_bounds__(256) void attn2_kernel(
    const unsigned short* __restrict__ qb,
    const unsigned short* __restrict__ kvb,
    const unsigned short* __restrict__ vt,
    const int* __restrict__ img_idx,
    unsigned short* __restrict__ attn_out) {
  __shared__ unsigned short Pl[4][64 * 72];
  const int tid = threadIdx.x;
  const int lane = tid & 63;
  const int w = tid >> 6;
  int bid = blockIdx.x;
  const int hg = bid & 3; bid >>= 2;
  const int tile = bid & 31; bid >>= 5;
  const int b = bid;
  const int t0 = tile * 64;
  const int h = hg * 4 + w;
  const int l15 = lane & 15;
  const int lg = lane >> 4;

  const int* ii = img_idx + b * T_ + t0;
  int myimg = ii[lane];
  int tmin = myimg, tmax = myimg;
#pragma unroll
  for (int off = 1; off < 64; off <<= 1) {
    tmin = min(tmin, __shfl_xor(tmin, off));
    tmax = max(tmax, __shfl_xor(tmax, off));
  }
  unsigned short* op = attn_out + (size_t)(b * T_ + t0) * INNER_ + h * DH_;
  if (tmin < 0) {
    for (int r = 0; r < 64; ++r)
      if (ii[r] < 0) op[(size_t)r * INNER_ + lane] = 0;
  }
  if (tmax < 0) return;

  bf16x8 qa[4][2];
  const unsigned short* qrow = qb + (size_t)(b * T_ + t0) * INNER_ + h * DH_;
#pragma unroll
  for (int m = 0; m < 4; ++m)
#pragma unroll
    for (int kk = 0; kk < 2; ++kk)
      qa[m][kk] = *(const bf16x8*)(qrow + (size_t)(l15 + m * 16) * INNER_ + kk * 32 + lg * 8);

  unsigned short* pw = Pl[w];
  for (int img = max(tmin, 0); img <= tmax; ++img) {
    const unsigned short* Kb = kvb + (size_t)(b * J_ + img * NLAT_) * (2 * INNER_) + h * DH_;
    f32x4 acc[4][4] = {};
#pragma unroll
    for (int kk = 0; kk < 2; ++kk) {
      bf16x8 bfr[4];
#pragma unroll
      for (int n = 0; n < 4; ++n)
        bfr[n] = *(const bf16x8*)(Kb + (size_t)(l15 + n * 16) * (2 * INNER_) + kk * 32 + lg * 8);
#pragma unroll
      for (int m = 0; m < 4; ++m)
#pragma unroll
        for (int n = 0; n < 4; ++n)
          acc[m][n] = __builtin_amdgcn_mfma_f32_16x16x32_bf16(qa[m][kk], bfr[n], acc[m][n], 0, 0, 0);
    }
#pragma unroll
    for (int m = 0; m < 4; ++m) {
#pragma unroll
      for (int j = 0; j < 4; ++j) {
        float mx = fmaxf(fmaxf(acc[m][0][j], acc[m][1][j]), fmaxf(acc[m][2][j], acc[m][3][j]));
#pragma unroll
        for (int off = 1; off < 16; off <<= 1) mx = fmaxf(mx, __shfl_xor(mx, off));
        float sum = 0.f;
#pragma unroll
        for (int n = 0; n < 4; ++n) {
          float e = __expf(acc[m][n][j] - mx);
          acc[m][n][j] = e;
          sum += e;
        }
#pragma unroll
        for (int off = 1; off < 16; off <<= 1) sum += __shfl_xor(sum, off);
        const float ri = 1.0f / sum;
        const int row = m * 16 + lg * 4 + j;
#pragma unroll
        for (int n = 0; n < 4; ++n)
          pw[row * 72 + n * 16 + l15] = f2bf(acc[m][n][j] * ri);
      }
    }
    const unsigned short* Vb = vt + (size_t)(b * INNER_ + h * DH_) * J_ + img * NLAT_;
    f32x4 oacc[4][4] = {};
#pragma unroll
    for (int kk = 0; kk < 2; ++kk) {
      bf16x8 pa[4], bfr[4];
#pragma unroll
      for (int m = 0; m < 4; ++m) {
        bf16x4 lo = *(const bf16x4*)(pw + (m * 16 + l15) * 72 + kk * 32 + lg * 8);
        bf16x4 hi = *(const bf16x4*)(pw + (m * 16 + l15) * 72 + kk * 32 + lg * 8 + 4);
        bf16x8 v;
#pragma unroll
        for (int e = 0; e < 4; ++e) { v[e] = lo[e]; v[e + 4] = hi[e]; }
        pa[m] = v;
      }
#pragma unroll
      for (int n = 0; n < 4; ++n)
        bfr[n] = *(const bf16x8*)(Vb + (size_t)(l15 + n * 16) * J_ + kk * 32 + lg * 8);
#pragma unroll
      for (int m = 0; m < 4; ++m)
#pragma unroll
        for (int n = 0; n < 4; ++n)
          oacc[m][n] = __builtin_amdgcn_mfma_f32_16x16x32_bf16(pa[m], bfr[n], oacc[m][n], 0, 0, 0);
    }
#pragma unroll
    for (int m = 0; m < 4; ++m)
#pragma unroll
      for (int j = 0; j < 4; ++j) {
        const int row = m * 16 + lg * 4 + j;
        if (ii[row] == img) {
#pragma unroll
          for (int n = 0; n < 4; ++n)
            op[(size_t)row * INNER_ + n * 16 + l15] = f2bf(oacc[m][n][j]);
        }
      }
  }
}

extern "C" void kernel_launch(void* const* d_in, const int* in_sizes, int n_in,
                              void* d_out, int out_size, void* d_ws, size_t ws_size,
                              hipStream_t stream) {
  const float* x = (const float*)d_in[0];
  const float* media = (const float*)d_in[1];
  const void* mloc = d_in[2];
  const float* gamma = (const float*)d_in[3];
  const float* beta = (const float*)d_in[4];
  const float* Wq = (const float*)d_in[5];
  const float* Wkv = (const float*)d_in[6];
  const float* Wout = (const float*)d_in[7];
  float* out = (float*)d_out;

  char* ws = (char*)d_ws;
  unsigned short* xn = (unsigned short*)(ws);
  unsigned short* wqt = (unsigned short*)(ws + 33554432);
  unsigned short* wkvt = (unsigned short*)(ws + 37748736);
  unsigned short* woutt = (unsigned short*)(ws + 41943040);
  unsigned short* medb = (unsigned short*)(ws + 46137344);
  unsigned short* qb = (unsigned short*)(ws + 50331648);
  unsigned short* kvb = (unsigned short*)(ws + 67108864);
  unsigned short* vt = (unsigned short*)(ws + 75497472);
  int* img_idx = (int*)(ws + 79691776);
  unsigned short* attn_out = xn;

  // fused prep: 8192 ln + 4 scan + 2048 x3 tcast + 2048 cast = 16388 blocks
  prep_kernel<<<16388, 256, 0, stream>>>(x, mloc, gamma, beta, Wq, Wkv, Wout, media,
                                         xn, img_idx, wqt, wkvt, woutt, medb);
  // GEMM1: q = xn @ wqt^T (M=8192,N=1024,K=2048) -> 256 blocks
  gemm_bt2<true><<<(B_ * T_ / 128) * (INNER_ / 256), 512, 0, stream>>>(xn, wqt, qb, B_ * T_, INNER_, D_);
  // GEMM2: kv = medb @ wkvt^T (M=2048,N=2048,K=1024) -> 128 blocks
  gemm_bt2<true><<<(B_ * J_ / 128) * (2 * INNER_ / 256), 512, 0, stream>>>(medb, wkvt, kvb, B_ * J_, 2 * INNER_, DV_);
  vtrans<<<dim3(J_ / 32, INNER_ / 32, B_), dim3(32, 8), 0, stream>>>(kvb, vt);
  attn2_kernel<<<B_ * (T_ / 64) * 4, 256, 0, stream>>>(qb, kvb, vt, img_idx, attn_out);
  // GEMM3: out = attn_out @ woutt^T (M=8192,N=2048,K=1024) -> 256 blocks
  gemm256<false><<<(B_ * T_ / 256) * (D_ / 256), 512, 0, stream>>>(attn_out, woutt, out, B_ * T_, D_, INNER_);
}